// Round 10
// baseline (1000.175 us; speedup 1.0000x reference)
//
#include <hip/hip_runtime.h>

typedef short bf16x8 __attribute__((ext_vector_type(8)));
typedef float f32x4 __attribute__((ext_vector_type(4)));

#define NS 131072
#define KC 2048
#define DD 256
#define SMARGIN 0.06f
#define ACHUNK 128

struct Rec16 { float m1, m2, m3; unsigned ii; };  // ii = i1 | (i2<<16)

// ---------------- helpers ----------------
__device__ __forceinline__ unsigned short f2bf(float x) {
  unsigned u = __float_as_uint(x);
  unsigned r = (u + 0x7fffu + ((u >> 16) & 1u)) >> 16;
  return (unsigned short)r;
}
__device__ __forceinline__ float bf2f(unsigned short b) {
  return __uint_as_float(((unsigned)b) << 16);
}
__device__ __forceinline__ unsigned umin_(unsigned a, unsigned b) { return a < b ? a : b; }
__device__ __forceinline__ unsigned umax_(unsigned a, unsigned b) { return a > b ? a : b; }

__device__ __forceinline__ void async16(void* lds, const void* g) {
  __builtin_amdgcn_global_load_lds(
      (const __attribute__((address_space(1))) unsigned*)g,
      (__attribute__((address_space(3))) unsigned*)lds, 16, 0, 0);
}

__device__ __forceinline__ void rec_ins(float& m1, float& m2, float& m3,
                                        int& i1, int& i2, float q, int i) {
  if (q < m1 || (q == m1 && i < i1)) {
    m3 = m2; m2 = m1; i2 = i1; m1 = q; i1 = i;
  } else if (q < m2 || (q == m2 && i < i2)) {
    m3 = m2; m2 = q; i2 = i;
  } else if (q < m3) {
    m3 = q;
  }
}

// exact fp32 distance: bit-identical to the verified round-2/3 chain
__device__ __forceinline__ float dist_exact(const float* __restrict__ E,
                                            const float* __restrict__ C,
                                            const float* __restrict__ x2,
                                            const float* __restrict__ c2,
                                            int row, int j) {
  const float* e = E + (size_t)row * DD;
  const float* c = C + (size_t)j * DD;
  float acc = 0.0f;
  #pragma unroll 8
  for (int k = 0; k < DD; ++k) acc = fmaf(e[k], c[k], acc);
  return __fadd_rn(__fsub_rn(x2[row], __fmul_rn(2.0f, acc)), c2[j]);
}

// ---------------- init ----------------
__global__ void k_init(int* __restrict__ cnt, double* __restrict__ loss,
                       int* __restrict__ npairs, int* __restrict__ nscan) {
  int i = blockIdx.x * 256 + threadIdx.x;
  if (i < KC) cnt[i] = 0;
  if (i == 0) { *loss = 0.0; *npairs = 0; *nscan = 0; }
}

// ---------------- row norms, numpy-pairwise-exact fp32 (proven) ----------
__global__ __launch_bounds__(256) void k_rownorm(const float* __restrict__ A,
                                                 float* __restrict__ out,
                                                 int nrows) {
  int g = blockIdx.x * 256 + threadIdx.x;
  int row = g >> 3;
  int l = g & 7;
  if (row >= nrows) return;
  const float* p = A + (size_t)row * DD;
  float halfs[2];
  #pragma unroll
  for (int h = 0; h < 2; ++h) {
    const float* q = p + h * 128;
    float x = q[l];
    float r = __fmul_rn(x, x);
    #pragma unroll
    for (int i = 8; i < 128; i += 8) {
      float y = q[i + l];
      r = __fadd_rn(r, __fmul_rn(y, y));
    }
    float t = __fadd_rn(r, __shfl_xor(r, 1));
    t = __fadd_rn(t, __shfl_xor(t, 2));
    t = __fadd_rn(t, __shfl_xor(t, 4));
    halfs[h] = t;
  }
  if (l == 0) out[row] = __fadd_rn(halfs[0], halfs[1]);
}

// ---------------- f32 -> (hi, lo) bf16 split (round-4 proven) ------------
__global__ __launch_bounds__(256) void k_split(const float* __restrict__ src,
                                               unsigned short* __restrict__ hi,
                                               unsigned short* __restrict__ lo,
                                               int n8) {
  int g = blockIdx.x * 256 + threadIdx.x;
  if (g >= n8) return;
  const float4* s = (const float4*)src;
  float4 v0 = s[(size_t)g * 2], v1 = s[(size_t)g * 2 + 1];
  float xs[8] = {v0.x, v0.y, v0.z, v0.w, v1.x, v1.y, v1.z, v1.w};
  ushort hv[8], lv[8];
  #pragma unroll
  for (int i = 0; i < 8; ++i) {
    unsigned short h = f2bf(xs[i]);
    hv[i] = h;
    lv[i] = f2bf(xs[i] - bf2f(h));
  }
  *(ulonglong2*)(hi + (size_t)g * 8) = *(ulonglong2*)hv;
  *(ulonglong2*)(lo + (size_t)g * 8) = *(ulonglong2*)lv;
}

// ---------------- MFMA screening GEMM + per-row approx top-3 ------------
// K' = 768 (hi*hi | hi*lo | lo*hi). 256x256 tile, BK=64, 8 waves (2x4),
// 8-phase counted-vmcnt schedule (T3+T4+T5), kh-granular double buffer.
// LDS buf p: A at p*65536 + kh*16384 (rows x 64B, chunk^=(row>>1)&3 swz),
//            B at p*65536 + 32768 + kh*16384.

#define VM8() do { asm volatile("s_waitcnt vmcnt(8)" ::: "memory"); \
                   __builtin_amdgcn_sched_barrier(0); } while (0)
#define VM4() do { asm volatile("s_waitcnt vmcnt(4)" ::: "memory"); \
                   __builtin_amdgcn_sched_barrier(0); } while (0)
#define VM0() do { asm volatile("s_waitcnt vmcnt(0)" ::: "memory"); \
                   __builtin_amdgcn_sched_barrier(0); } while (0)

#define LOAD_A2(p, ks) { _Pragma("unroll") for (int m_ = 0; m_ < 8; ++m_) \
    a[m_] = *(const bf16x8*)(smem + (p)*65536 + (ks)*16384 + aoff[m_] + csw2); }
#define LOAD_B2(p, ks, nh) { _Pragma("unroll") for (int n_ = 0; n_ < 2; ++n_) \
    bfr[n_] = *(const bf16x8*)(smem + (p)*65536 + 32768 + (ks)*16384 + boff[(nh)*2+n_] + csw2); }
#define MFMA_QN(nh) { _Pragma("unroll") for (int m_ = 0; m_ < 8; ++m_) \
    _Pragma("unroll") for (int n_ = 0; n_ < 2; ++n_) \
      acc[m_][(nh)*2+n_] = __builtin_amdgcn_mfma_f32_16x16x32_bf16( \
          a[m_], bfr[n_], acc[m_][(nh)*2+n_], 0, 0, 0); }

#define STAGE_A2(p, kh, S) { \
    char* _d = smem + (p)*65536 + (kh)*16384 + wave*2048; \
    const unsigned short* _s = (((S)>>2)==2 ? pElo : pEhi) + (kh)*32 + (((S)&3)*64); \
    async16(_d, _s); async16(_d + 1024, _s + 4096); }
#define STAGE_B2(p, kh, S) { \
    char* _d = smem + (p)*65536 + 32768 + (kh)*16384 + wave*2048; \
    const unsigned short* _s = (((S)>>2)==1 ? pClo : pChi) + (kh)*32 + (((S)&3)*64); \
    async16(_d, _s); async16(_d + 1024, _s + 4096); }

#define MID_MFMA(nh) \
    __builtin_amdgcn_s_barrier(); \
    asm volatile("s_waitcnt lgkmcnt(0)" ::: "memory"); \
    __builtin_amdgcn_sched_barrier(0); \
    __builtin_amdgcn_s_setprio(1); \
    MFMA_QN(nh); \
    __builtin_amdgcn_s_setprio(0);

#define ENDP() __builtin_amdgcn_s_barrier();

#define ITER(i) { \
    /* ph1: buf0 ks0 nh0 */ \
    LOAD_A2(0, 0); LOAD_B2(0, 0, 0); \
    if ((i) > 0) STAGE_A2(1, 1, 2*(i)+1); \
    MID_MFMA(0); ENDP(); \
    /* ph2 */ \
    LOAD_B2(0, 0, 1); \
    if ((i) > 0) STAGE_B2(1, 1, 2*(i)+1); \
    MID_MFMA(1); VM8(); ENDP(); \
    /* ph3: buf0 ks1 nh0 */ \
    LOAD_A2(0, 1); LOAD_B2(0, 1, 0); \
    if (2*(i)+2 < 12) STAGE_A2(0, 0, 2*(i)+2); \
    MID_MFMA(0); ENDP(); \
    /* ph4 */ \
    LOAD_B2(0, 1, 1); \
    if (2*(i)+2 < 12) STAGE_B2(0, 0, 2*(i)+2); \
    MID_MFMA(1); if ((i) < 5) { VM8(); } else { VM4(); } ENDP(); \
    /* ph5: buf1 ks0 nh0 */ \
    LOAD_A2(1, 0); LOAD_B2(1, 0, 0); \
    if (2*(i)+2 < 12) STAGE_A2(0, 1, 2*(i)+2); \
    MID_MFMA(0); ENDP(); \
    /* ph6 */ \
    LOAD_B2(1, 0, 1); \
    if (2*(i)+2 < 12) STAGE_B2(0, 1, 2*(i)+2); \
    MID_MFMA(1); if ((i) < 5) { VM8(); } else { VM0(); } ENDP(); \
    /* ph7: buf1 ks1 nh0 */ \
    LOAD_A2(1, 1); LOAD_B2(1, 1, 0); \
    if (2*(i)+3 < 12) STAGE_A2(1, 0, 2*(i)+3); \
    MID_MFMA(0); ENDP(); \
    /* ph8 */ \
    LOAD_B2(1, 1, 1); \
    if (2*(i)+3 < 12) STAGE_B2(1, 0, 2*(i)+3); \
    MID_MFMA(1); if ((i) < 5) { VM8(); } ENDP(); \
}

__global__ __launch_bounds__(512, 1) void k_screen(
    const unsigned short* __restrict__ Ehi, const unsigned short* __restrict__ Elo,
    const unsigned short* __restrict__ Chi, const unsigned short* __restrict__ Clo,
    const float* __restrict__ c2, Rec16* __restrict__ recs, int rowOff) {
  __shared__ char smem[131072];

  const int tid = threadIdx.x;
  const int wave = tid >> 6, lane = tid & 63;
  const int ln15 = lane & 15, ln4 = lane >> 4;       // ln4: 0..3
  const int wr = wave >> 2, wc = wave & 3;           // 2 x 4 wave grid
  const int nwg = gridDim.x;
  const int b = blockIdx.x;
  const int swzb = (b & 7) * (nwg >> 3) + (b >> 3);  // bijective: nwg % 8 == 0
  const int colblk = swzb & 7, rowblk = swzb >> 3;
  const int rowA0 = rowblk * 256, colB0 = colblk * 256;

  // staging source swizzle: lane l covers row (l>>2), chunk (l&3);
  // LDS slot (row, cs) holds global chunk cs ^ ((row>>1)&3) = cs ^ ((l>>3)&3)
  const int ssw = (((lane & 3) ^ ((lane >> 3) & 3)) * 8);
  const unsigned short* pEhi = Ehi + (size_t)(rowA0 + wave * 32 + (lane >> 2)) * 256 + ssw;
  const unsigned short* pElo = Elo + (size_t)(rowA0 + wave * 32 + (lane >> 2)) * 256 + ssw;
  const unsigned short* pChi = Chi + (size_t)(colB0 + wave * 32 + (lane >> 2)) * 256 + ssw;
  const unsigned short* pClo = Clo + (size_t)(colB0 + wave * 32 + (lane >> 2)) * 256 + ssw;

  // hoisted ds_read offsets
  int aoff[8], boff[4];
  #pragma unroll
  for (int m = 0; m < 8; ++m) aoff[m] = (wr * 128 + m * 16 + ln15) * 64;
  #pragma unroll
  for (int n = 0; n < 4; ++n) boff[n] = (wc * 64 + n * 16 + ln15) * 64;
  const int csw2 = ((ln4 ^ ((ln15 >> 1) & 3)) << 4);

  f32x4 acc[8][4];
  #pragma unroll
  for (int m = 0; m < 8; ++m)
    #pragma unroll
    for (int n = 0; n < 4; ++n) acc[m][n] = (f32x4){0.f, 0.f, 0.f, 0.f};
  bf16x8 a[8], bfr[2];

  // prologue: K-step 0 -> buf0, K-step 1 -> buf1 (kh0 first within each)
  STAGE_A2(0, 0, 0); STAGE_B2(0, 0, 0); STAGE_A2(0, 1, 0); STAGE_B2(0, 1, 0);
  STAGE_A2(1, 0, 1); STAGE_B2(1, 0, 1); STAGE_A2(1, 1, 1); STAGE_B2(1, 1, 1);
  VM8();
  __builtin_amdgcn_s_barrier();

  ITER(0) ITER(1) ITER(2) ITER(3) ITER(4) ITER(5)

  __syncthreads();

  // ---- epilogue: sortable keys (col in low 8 bits), per-row top-3 ------
  float c2v[4];
  #pragma unroll
  for (int n = 0; n < 4; ++n) c2v[n] = c2[colB0 + wc * 64 + n * 16 + ln15];

  uint4* trip = (uint4*)smem;  // [256 rows][4 wc]
  #pragma unroll
  for (int m = 0; m < 8; ++m) {
    #pragma unroll
    for (int rr = 0; rr < 4; ++rr) {
      unsigned k1 = 0xFFFFFFFFu, k2 = 0xFFFFFFFFu, k3 = 0xFFFFFFFFu;
      #pragma unroll
      for (int n = 0; n < 4; ++n) {
        float q = fmaf(-2.0f, acc[m][n][rr], c2v[n]);
        unsigned u = __float_as_uint(q);
        unsigned msk = 0x80000000u | (unsigned)((int)u >> 31);
        unsigned key = ((u ^ msk) & 0xFFFFFF00u) | (unsigned)(wc * 64 + n * 16 + ln15);
        unsigned t1 = umax_(k1, key); k1 = umin_(k1, key);
        unsigned t2 = umax_(k2, t1);  k2 = umin_(k2, t1);
        k3 = umin_(k3, t2);
      }
      #pragma unroll
      for (int sh = 1; sh <= 8; sh <<= 1) {
        unsigned o1 = (unsigned)__shfl_xor((int)k1, sh);
        unsigned o2 = (unsigned)__shfl_xor((int)k2, sh);
        unsigned o3 = (unsigned)__shfl_xor((int)k3, sh);
        unsigned mm = umax_(k1, o1); k1 = umin_(k1, o1);
        unsigned tt = umin_(k2, o2);
        k2 = umin_(mm, tt);
        k3 = umin_(umin_(k3, o3), umax_(mm, tt));
      }
      if (ln15 == 0) {
        int row_l = wr * 128 + m * 16 + ln4 * 4 + rr;
        trip[row_l * 4 + wc] = make_uint4(k1, k2, k3, 0u);
      }
    }
  }
  __syncthreads();
  if (tid < 256) {
    uint4 t0 = trip[tid * 4 + 0];
    unsigned k1 = t0.x, k2 = t0.y, k3 = t0.z;
    #pragma unroll
    for (int w = 1; w < 4; ++w) {
      uint4 tw = trip[tid * 4 + w];
      unsigned c1 = tw.x;
      unsigned a1 = umax_(k1, c1); k1 = umin_(k1, c1);
      unsigned a2 = umax_(k2, a1); k2 = umin_(k2, a1); k3 = umin_(k3, a2);
      unsigned c2k = tw.y;
      unsigned b1 = umax_(k1, c2k); k1 = umin_(k1, c2k);
      unsigned b2 = umax_(k2, b1); k2 = umin_(k2, b1); k3 = umin_(k3, b2);
      k3 = umin_(k3, tw.z);
    }
    auto dec = [](unsigned k) -> float {
      unsigned u = k & 0xFFFFFF00u;
      u = (u & 0x80000000u) ? (u ^ 0x80000000u) : ~u;
      return __uint_as_float(u);
    };
    Rec16 outr;
    outr.m1 = dec(k1); outr.m2 = dec(k2); outr.m3 = dec(k3);
    int i1 = colB0 + (int)(k1 & 255u);
    int i2 = colB0 + (int)(k2 & 255u);
    outr.ii = (unsigned)i1 | ((unsigned)i2 << 16);
    recs[((size_t)(rowOff + rowA0 + tid) << 3) + colblk] = outr;
  }
}

// ---------------- merge 8 col-block records; classify rows --------------
__global__ __launch_bounds__(256) void k_merge(
    const Rec16* __restrict__ recs, int* __restrict__ labels,
    int4* __restrict__ pairs, int* __restrict__ scans,
    int* __restrict__ npairs, int* __restrict__ nscan) {
  int row = blockIdx.x * 256 + threadIdx.x;
  const Rec16* r = recs + ((size_t)row << 3);
  Rec16 a = r[0];
  float m1 = a.m1, m2 = a.m2, m3 = a.m3;
  int i1 = (int)(a.ii & 0xffffu), i2 = (int)(a.ii >> 16);
  #pragma unroll
  for (int cb = 1; cb < 8; ++cb) {
    Rec16 bb = r[cb];
    rec_ins(m1, m2, m3, i1, i2, bb.m1, (int)(bb.ii & 0xffffu));
    rec_ins(m1, m2, m3, i1, i2, bb.m2, (int)(bb.ii >> 16));
    m3 = fminf(m3, bb.m3);
  }
  labels[row] = i1;
  if (m2 <= m1 + SMARGIN) {
    if (m3 <= m1 + SMARGIN) {
      int s = atomicAdd(nscan, 1); scans[s] = row;
    } else {
      int p = atomicAdd(npairs, 1); pairs[p] = make_int4(row, i1, i2, 0);
    }
  }
}

// ---------------- exact rescore: 2-candidate rows ----------------
__global__ __launch_bounds__(256) void k_pairs(
    const float* __restrict__ E, const float* __restrict__ C,
    const float* __restrict__ x2, const float* __restrict__ c2,
    const int4* __restrict__ pairs, const int* __restrict__ npairs,
    int* __restrict__ labels) {
  int n = *npairs;
  int stride = gridDim.x * 256;
  for (int i = blockIdx.x * 256 + threadIdx.x; i < n; i += stride) {
    int4 p = pairs[i];
    float d1 = dist_exact(E, C, x2, c2, p.x, p.y);
    float d2 = dist_exact(E, C, x2, c2, p.x, p.z);
    labels[p.x] = (d2 < d1 || (d2 == d1 && p.z < p.y)) ? p.z : p.y;
  }
}

// ---------------- exact rescore: full-scan rows ----------------
__global__ __launch_bounds__(256) void k_scan(
    const float* __restrict__ E, const float* __restrict__ C,
    const float* __restrict__ x2, const float* __restrict__ c2,
    const int* __restrict__ scans, const int* __restrict__ nscan,
    int* __restrict__ labels) {
  __shared__ float sd[256];
  __shared__ int sj[256];
  int ns = *nscan;
  for (int s = blockIdx.x; s < ns; s += gridDim.x) {
    int row = scans[s];
    float bd = 3.4e38f; int bj = 0x7fffffff;
    for (int jj = 0; jj < 8; ++jj) {
      int j = jj * 256 + threadIdx.x;
      float d = dist_exact(E, C, x2, c2, row, j);
      if (d < bd || (d == bd && j < bj)) { bd = d; bj = j; }
    }
    sd[threadIdx.x] = bd; sj[threadIdx.x] = bj;
    __syncthreads();
    for (int st = 128; st > 0; st >>= 1) {
      if (threadIdx.x < st) {
        float od = sd[threadIdx.x + st]; int oj = sj[threadIdx.x + st];
        if (od < sd[threadIdx.x] || (od == sd[threadIdx.x] && oj < sj[threadIdx.x])) {
          sd[threadIdx.x] = od; sj[threadIdx.x] = oj;
        }
      }
      __syncthreads();
    }
    if (threadIdx.x == 0) labels[row] = sj[0];
    __syncthreads();
  }
}

// ---------------- histogram of final labels ----------------
__global__ void k_hist(const int* __restrict__ labels, int* __restrict__ cnt) {
  int i = blockIdx.x * 256 + threadIdx.x;
  if (i < NS) atomicAdd(&cnt[labels[i]], 1);
}

// ---------------- exclusive scan over 2048 counts (Blelloch) ------------
__global__ __launch_bounds__(1024) void k_prefix(const int* __restrict__ cnt,
                                                 int* __restrict__ offs,
                                                 int* __restrict__ cursors) {
  __shared__ int s[KC];
  int t = threadIdx.x;
  s[t] = cnt[t]; s[t + 1024] = cnt[t + 1024];
  int offset = 1;
  for (int d = KC >> 1; d > 0; d >>= 1) {
    __syncthreads();
    if (t < d) {
      int ai = offset * (2 * t + 1) - 1;
      int bi = offset * (2 * t + 2) - 1;
      s[bi] += s[ai];
    }
    offset <<= 1;
  }
  __syncthreads();
  if (t == 0) s[KC - 1] = 0;
  for (int d = 1; d < KC; d <<= 1) {
    offset >>= 1;
    __syncthreads();
    if (t < d) {
      int ai = offset * (2 * t + 1) - 1;
      int bi = offset * (2 * t + 2) - 1;
      int tmp = s[ai]; s[ai] = s[bi]; s[bi] += tmp;
    }
  }
  __syncthreads();
  offs[t] = s[t];               cursors[t] = s[t];
  offs[t + 1024] = s[t + 1024]; cursors[t + 1024] = s[t + 1024];
  if (t == 0) offs[KC] = NS;
}

// ---------------- scatter rows into label-sorted order (+label array) ----
__global__ void k_scatter(const int* __restrict__ labels, int* __restrict__ cursors,
                          int* __restrict__ sorted, int* __restrict__ slab,
                          float* __restrict__ out_labels) {
  int i = blockIdx.x * 256 + threadIdx.x;
  if (i < NS) {
    int lab = labels[i];
    out_labels[i] = (float)lab;
    int pos = atomicAdd(&cursors[lab], 1);
    sorted[pos] = i;
    slab[pos] = lab;
  }
}

// ---------------- balanced segmented accumulate over sorted rows --------
__global__ __launch_bounds__(256) void k_accum3(
    const float* __restrict__ E, const float* __restrict__ C,
    const int* __restrict__ sorted, const int* __restrict__ slab,
    float* __restrict__ seg, double* __restrict__ loss) {
  const int d = threadIdx.x;
  const int beg = blockIdx.x * ACHUNK;
  const int end = beg + ACHUNK;
  int cur = slab[beg];
  float sum = 0.0f;
  double lp = 0.0;
  for (int i = beg; i < end; ++i) {
    int lab = slab[i];
    if (lab != cur) {
      unsafeAtomicAdd(&seg[(size_t)cur * DD + d], sum);
      sum = 0.0f; cur = lab;
    }
    float x = E[(size_t)sorted[i] * DD + d];
    sum += x;
    float c = C[(size_t)lab * DD + d];
    float df = x - c;
    lp += (double)df * (double)df;
  }
  unsafeAtomicAdd(&seg[(size_t)cur * DD + d], sum);
  #pragma unroll
  for (int o = 32; o >= 1; o >>= 1) lp += __shfl_down(lp, o);
  __shared__ double wsum[4];
  int lane = d & 63, wv = d >> 6;
  if (lane == 0) wsum[wv] = lp;
  __syncthreads();
  if (d == 0) unsafeAtomicAdd(loss, wsum[0] + wsum[1] + wsum[2] + wsum[3]);
}

// ---------------- init seg region (= out_centers) ----------------
__global__ void k_zeroseg(float* __restrict__ segc) {
  int i = blockIdx.x * 256 + threadIdx.x;
  if (i < KC * DD) segc[i] = 0.0f;
}

// ---------------- finalize centers, counts, loss ----------------
__global__ void k_final2(const float* __restrict__ C, const int* __restrict__ counts0,
                         const int* __restrict__ offs, float* __restrict__ out_centers,
                         float* __restrict__ out_counts, float* __restrict__ out_loss,
                         const double* __restrict__ loss) {
  int i = blockIdx.x * 256 + threadIdx.x;
  if (i < KC * DD) {
    int k = i >> 8;
    float c0 = (float)counts0[k];
    float nc = c0 + (float)(offs[k + 1] - offs[k]);
    out_centers[i] = (c0 * C[i] + out_centers[i]) / nc;
  }
  if (i < KC) out_counts[i] = (float)counts0[i] + (float)(offs[i + 1] - offs[i]);
  if (i == 0) out_loss[0] = (float)(loss[0] / (double)NS);
}

extern "C" void kernel_launch(void* const* d_in, const int* in_sizes, int n_in,
                              void* d_out, int out_size, void* d_ws, size_t ws_size,
                              hipStream_t stream) {
  const float* E = (const float*)d_in[0];
  const float* C = (const float*)d_in[1];
  const int* counts0 = (const int*)d_in[2];

  float* out = (float*)d_out;
  float* out_labels  = out;                     // [NS]
  float* out_loss    = out + NS;                // [1]
  float* out_centers = out + NS + 1;            // [KC*DD] (doubles as seg acc)
  float* out_counts  = out + NS + 1 + KC * DD;  // [KC]

  char* ws = (char*)d_ws;
  size_t o = 0;
  auto alloc = [&](size_t bytes) -> void* {
    void* p = ws + o;
    o += (bytes + 255) & ~(size_t)255;
    return p;
  };
  double* loss_acc = (double*)alloc(256);  // loss @0, npairs @16, nscan @20
  int* npairs = (int*)((char*)loss_acc + 16);
  int* nscan  = (int*)((char*)loss_acc + 20);
  int*   labels  = (int*)alloc(4 * (size_t)NS);
  float* x2      = (float*)alloc(4 * (size_t)NS);
  float* c2      = (float*)alloc(4 * KC);
  int*   cnt     = (int*)alloc(4 * KC);
  int*   offs    = (int*)alloc(4 * (KC + 1));
  int*   cursors = (int*)alloc(4 * KC);
  int*   sorted  = (int*)alloc(4 * (size_t)NS);
  int*   slab    = (int*)alloc(4 * (size_t)NS);
  unsigned short* Chi = (unsigned short*)alloc(2 * (size_t)KC * DD);
  unsigned short* Clo = (unsigned short*)alloc(2 * (size_t)KC * DD);
  Rec16* recs    = (Rec16*)alloc(sizeof(Rec16) * (size_t)NS * 8);
  int4*  pairs   = (int4*)alloc(16 * (size_t)NS);
  int*   scans   = (int*)alloc(4 * (size_t)NS);

  // E hi/lo chunk: full NS if it fits, else halve (min 2048 rows = 8 rowblks)
  size_t avail = (ws_size > o) ? (ws_size - o) : 0;
  int CH = NS;
  while (CH > 2048 && 2 * (2 * (size_t)CH * DD) > avail) CH >>= 1;
  unsigned short* Ehi = (unsigned short*)alloc(2 * (size_t)CH * DD);
  unsigned short* Elo = (unsigned short*)alloc(2 * (size_t)CH * DD);
  int NCH = NS / CH;

  hipLaunchKernelGGL(k_init, dim3(8), dim3(256), 0, stream,
                     cnt, loss_acc, npairs, nscan);
  hipLaunchKernelGGL(k_zeroseg, dim3((KC * DD + 255) / 256), dim3(256), 0, stream,
                     out_centers);
  hipLaunchKernelGGL(k_rownorm, dim3(NS * 8 / 256), dim3(256), 0, stream, E, x2, NS);
  hipLaunchKernelGGL(k_rownorm, dim3(KC * 8 / 256), dim3(256), 0, stream, C, c2, KC);
  hipLaunchKernelGGL(k_split, dim3(KC * 32 / 256), dim3(256), 0, stream,
                     C, Chi, Clo, KC * 32);

  for (int ch = 0; ch < NCH; ++ch) {
    hipLaunchKernelGGL(k_split, dim3(CH * 32 / 256), dim3(256), 0, stream,
                       E + (size_t)ch * CH * DD, Ehi, Elo, CH * 32);
    hipLaunchKernelGGL(k_screen, dim3((CH / 256) * 8), dim3(512), 0, stream,
                       Ehi, Elo, Chi, Clo, c2, recs, ch * CH);
  }

  hipLaunchKernelGGL(k_merge, dim3(NS / 256), dim3(256), 0, stream,
                     recs, labels, pairs, scans, npairs, nscan);
  hipLaunchKernelGGL(k_pairs, dim3(64), dim3(256), 0, stream,
                     E, C, x2, c2, pairs, npairs, labels);
  hipLaunchKernelGGL(k_scan, dim3(128), dim3(256), 0, stream,
                     E, C, x2, c2, scans, nscan, labels);
  hipLaunchKernelGGL(k_hist, dim3(NS / 256), dim3(256), 0, stream, labels, cnt);
  hipLaunchKernelGGL(k_prefix, dim3(1), dim3(1024), 0, stream, cnt, offs, cursors);
  hipLaunchKernelGGL(k_scatter, dim3(NS / 256), dim3(256), 0, stream,
                     labels, cursors, sorted, slab, out_labels);
  hipLaunchKernelGGL(k_accum3, dim3(NS / ACHUNK), dim3(256), 0, stream,
                     E, C, sorted, slab, out_centers, loss_acc);
  hipLaunchKernelGGL(k_final2, dim3((KC * DD + 255) / 256), dim3(256), 0, stream,
                     C, counts0, offs, out_centers, out_counts, out_loss, loss_acc);
}

// Round 11
// 875.561 us; speedup vs baseline: 1.1423x; 1.1423x over previous
//
#include <hip/hip_runtime.h>

typedef _Float16 f16x8 __attribute__((ext_vector_type(8)));
typedef float f32x4 __attribute__((ext_vector_type(4)));

#define NS 131072
#define KC 2048
#define DD 256
#define SMARGIN 0.12f
#define ACHUNK 128

struct Rec16 { float m1, m2, m3; unsigned ii; };  // ii = i1 | (i2<<16)

// ---------------- helpers ----------------
__device__ __forceinline__ unsigned umin_(unsigned a, unsigned b) { return a < b ? a : b; }
__device__ __forceinline__ unsigned umax_(unsigned a, unsigned b) { return a > b ? a : b; }

__device__ __forceinline__ void async16(void* lds, const void* g) {
  __builtin_amdgcn_global_load_lds(
      (const __attribute__((address_space(1))) unsigned*)g,
      (__attribute__((address_space(3))) unsigned*)lds, 16, 0, 0);
}

__device__ __forceinline__ void rec_ins(float& m1, float& m2, float& m3,
                                        int& i1, int& i2, float q, int i) {
  if (q < m1 || (q == m1 && i < i1)) {
    m3 = m2; m2 = m1; i2 = i1; m1 = q; i1 = i;
  } else if (q < m2 || (q == m2 && i < i2)) {
    m3 = m2; m2 = q; i2 = i;
  } else if (q < m3) {
    m3 = q;
  }
}

// exact fp32 distance: bit-identical to the verified round-2/3 chain
__device__ __forceinline__ float dist_exact(const float* __restrict__ E,
                                            const float* __restrict__ C,
                                            const float* __restrict__ x2,
                                            const float* __restrict__ c2,
                                            int row, int j) {
  const float* e = E + (size_t)row * DD;
  const float* c = C + (size_t)j * DD;
  float acc = 0.0f;
  #pragma unroll 8
  for (int k = 0; k < DD; ++k) acc = fmaf(e[k], c[k], acc);
  return __fadd_rn(__fsub_rn(x2[row], __fmul_rn(2.0f, acc)), c2[j]);
}

// ---------------- init ----------------
__global__ void k_init(int* __restrict__ cnt, double* __restrict__ loss,
                       int* __restrict__ npairs, int* __restrict__ nscan) {
  int i = blockIdx.x * 256 + threadIdx.x;
  if (i < KC) cnt[i] = 0;
  if (i == 0) { *loss = 0.0; *npairs = 0; *nscan = 0; }
}

// ---------------- row norms, numpy-pairwise-exact fp32 (proven) ----------
__global__ __launch_bounds__(256) void k_rownorm(const float* __restrict__ A,
                                                 float* __restrict__ out,
                                                 int nrows) {
  int g = blockIdx.x * 256 + threadIdx.x;
  int row = g >> 3;
  int l = g & 7;
  if (row >= nrows) return;
  const float* p = A + (size_t)row * DD;
  float halfs[2];
  #pragma unroll
  for (int h = 0; h < 2; ++h) {
    const float* q = p + h * 128;
    float x = q[l];
    float r = __fmul_rn(x, x);
    #pragma unroll
    for (int i = 8; i < 128; i += 8) {
      float y = q[i + l];
      r = __fadd_rn(r, __fmul_rn(y, y));
    }
    float t = __fadd_rn(r, __shfl_xor(r, 1));
    t = __fadd_rn(t, __shfl_xor(t, 2));
    t = __fadd_rn(t, __shfl_xor(t, 4));
    halfs[h] = t;
  }
  if (l == 0) out[row] = __fadd_rn(halfs[0], halfs[1]);
}

// ---------------- f32 -> fp16 (hi | lo) packed row of 512 (E side) ------
__global__ __launch_bounds__(256) void k_split16(const float* __restrict__ src,
                                                 unsigned short* __restrict__ dst,
                                                 int n32) {
  int g = blockIdx.x * 256 + threadIdx.x;
  if (g >= n32) return;
  int row = g >> 5, seg = g & 31;
  const float4* s = (const float4*)(src + (size_t)row * DD + seg * 8);
  float4 v0 = s[0], v1 = s[1];
  float xs[8] = {v0.x, v0.y, v0.z, v0.w, v1.x, v1.y, v1.z, v1.w};
  unsigned short hv[8], lv[8];
  #pragma unroll
  for (int i = 0; i < 8; ++i) {
    union { _Float16 h; unsigned short u; } ch, cl;
    ch.h = (_Float16)xs[i];
    cl.h = (_Float16)(xs[i] - (float)ch.h);
    hv[i] = ch.u; lv[i] = cl.u;
  }
  unsigned short* d = dst + (size_t)row * 512 + seg * 8;
  *(ulonglong2*)d = *(ulonglong2*)hv;
  *(ulonglong2*)(d + 256) = *(ulonglong2*)lv;
}

// ---------------- f32 -> fp16 hi only (C side, row of 256) --------------
__global__ __launch_bounds__(256) void k_split16c(const float* __restrict__ src,
                                                  unsigned short* __restrict__ dst,
                                                  int n32) {
  int g = blockIdx.x * 256 + threadIdx.x;
  if (g >= n32) return;
  int row = g >> 5, seg = g & 31;
  const float4* s = (const float4*)(src + (size_t)row * DD + seg * 8);
  float4 v0 = s[0], v1 = s[1];
  float xs[8] = {v0.x, v0.y, v0.z, v0.w, v1.x, v1.y, v1.z, v1.w};
  unsigned short hv[8];
  #pragma unroll
  for (int i = 0; i < 8; ++i) {
    union { _Float16 h; unsigned short u; } ch;
    ch.h = (_Float16)xs[i];
    hv[i] = ch.u;
  }
  *(ulonglong2*)(dst + (size_t)row * 256 + seg * 8) = *(ulonglong2*)hv;
}

// ---------------- MFMA screening GEMM + per-row approx top-3 ------------
// fp16 split: dot = (hi_x+lo_x)·hi_c over K'=512 (A = [hi|lo], B slab
// reuses hi_c via k0 = (s&3)*64). 128x128 tile, BK=64, 4 waves (2x2),
// 2-phase double-buffered LDS (round-8 proven structure), 8 slabs.
__global__ __launch_bounds__(256, 2) void k_screen16(
    const unsigned short* __restrict__ EX, const unsigned short* __restrict__ CX,
    const float* __restrict__ c2, Rec16* __restrict__ recs, int rowOff) {
  __shared__ char smem[65536];  // 2 bufs x (A 16K | B 16K)

  const int nwg = gridDim.x;
  const int b = blockIdx.x;
  const int swzb = (b & 7) * (nwg >> 3) + (b >> 3);   // bijective: nwg % 8 == 0
  const int colblk = swzb & 15, rowblk = swzb >> 4;

  const int tid = threadIdx.x;
  const int wave = tid >> 6, lane = tid & 63;
  const int ln15 = lane & 15, ln4 = lane >> 4;
  const int wr = wave >> 1, wc = wave & 1;
  const int rowA0 = rowblk * 128;
  const int colB0 = colblk * 128;
  const int rsw = ((lane & 7) ^ (lane >> 3)) << 3;  // src pre-swizzle (elems)

  // hoisted global staging pointers (per t-round of 8 rows)
  const unsigned short* pA[4];
  const unsigned short* pB[4];
  {
    size_t ra = (size_t)(rowA0 + wave * 32 + (lane >> 3)) * 512 + rsw;
    size_t rb = (size_t)(colB0 + wave * 32 + (lane >> 3)) * 256 + rsw;
    #pragma unroll
    for (int t = 0; t < 4; ++t) {
      pA[t] = EX + ra + t * 4096;   // t*8 rows x 512
      pB[t] = CX + rb + t * 2048;   // t*8 rows x 256
    }
  }
  // wave-uniform LDS staging bases
  char* ldsA = smem + wave * 4096;
  char* ldsB = smem + 16384 + wave * 4096;
  // hoisted swizzled ds_read addresses [ks][frag]
  const char* aaddr[2][4];
  const char* baddr[2][4];
  #pragma unroll
  for (int ks = 0; ks < 2; ++ks) {
    int sz = ((ks * 4 + ln4) ^ (ln15 & 7)) << 4;
    #pragma unroll
    for (int m = 0; m < 4; ++m)
      aaddr[ks][m] = smem + (wr * 64 + m * 16 + ln15) * 128 + sz;
    #pragma unroll
    for (int n = 0; n < 4; ++n)
      baddr[ks][n] = smem + 16384 + (wc * 64 + n * 16 + ln15) * 128 + sz;
  }

  f32x4 acc[4][4];
  #pragma unroll
  for (int m = 0; m < 4; ++m)
    #pragma unroll
    for (int n = 0; n < 4; ++n) acc[m][n] = (f32x4){0.f, 0.f, 0.f, 0.f};

#define STAGE(s) {                                                        \
    const int _buf = (s) & 1;                                             \
    const int _ka = (s) * 64;                                             \
    const int _kb = ((s) & 3) * 64;                                       \
    _Pragma("unroll")                                                     \
    for (int t = 0; t < 4; ++t) {                                         \
      async16(ldsA + _buf * 32768 + t * 1024, pA[t] + _ka);               \
      async16(ldsB + _buf * 32768 + t * 1024, pB[t] + _kb);               \
    } }

#define COMPUTE(s) {                                                      \
    const int _bo = ((s) & 1) * 32768;                                    \
    _Pragma("unroll")                                                     \
    for (int ks = 0; ks < 2; ++ks) {                                      \
      f16x8 a[4], bb[4];                                                  \
      _Pragma("unroll")                                                   \
      for (int m = 0; m < 4; ++m)                                         \
        a[m] = *(const f16x8*)(aaddr[ks][m] + _bo);                       \
      _Pragma("unroll")                                                   \
      for (int n = 0; n < 4; ++n)                                         \
        bb[n] = *(const f16x8*)(baddr[ks][n] + _bo);                      \
      _Pragma("unroll")                                                   \
      for (int m = 0; m < 4; ++m)                                         \
        _Pragma("unroll")                                                 \
        for (int n = 0; n < 4; ++n)                                       \
          acc[m][n] = __builtin_amdgcn_mfma_f32_16x16x32_f16(             \
              a[m], bb[n], acc[m][n], 0, 0, 0);                           \
    } }

  STAGE(0);
  __syncthreads();
  #pragma unroll
  for (int s = 0; s < 8; ++s) {
    if (s < 7) STAGE(s + 1);
    COMPUTE(s);
    __syncthreads();
  }
#undef STAGE
#undef COMPUTE

  // ---- branchless epilogue: sortable-u32 keys, col packed in low 6 bits
  float c2v[4];
  #pragma unroll
  for (int n = 0; n < 4; ++n) c2v[n] = c2[colB0 + wc * 64 + n * 16 + ln15];

  unsigned* mb = (unsigned*)smem;  // [128 rows][2 wc][4 words]
  #pragma unroll
  for (int m = 0; m < 4; ++m) {
    #pragma unroll
    for (int rr = 0; rr < 4; ++rr) {
      unsigned k1 = 0xFFFFFFFFu, k2 = 0xFFFFFFFFu, k3 = 0xFFFFFFFFu;
      #pragma unroll
      for (int n = 0; n < 4; ++n) {
        float q = fmaf(-2.0f, acc[m][n][rr], c2v[n]);
        unsigned u = __float_as_uint(q);
        unsigned msk = 0x80000000u | (unsigned)((int)u >> 31);
        unsigned key = ((u ^ msk) & 0xFFFFFFC0u) | (unsigned)(n * 16 + ln15);
        unsigned t1 = umax_(k1, key);
        k1 = umin_(k1, key);
        unsigned t2 = umax_(k2, t1);
        k2 = umin_(k2, t1);
        k3 = umin_(k3, t2);
      }
      #pragma unroll
      for (int sh = 1; sh <= 8; sh <<= 1) {
        unsigned o1 = (unsigned)__shfl_xor((int)k1, sh);
        unsigned o2 = (unsigned)__shfl_xor((int)k2, sh);
        unsigned o3 = (unsigned)__shfl_xor((int)k3, sh);
        unsigned mm = umax_(k1, o1);
        k1 = umin_(k1, o1);
        unsigned tt = umin_(k2, o2);
        k2 = umin_(mm, tt);
        k3 = umin_(umin_(k3, o3), umax_(mm, tt));
      }
      if (ln15 == 0) {
        int row = wr * 64 + m * 16 + ln4 * 4 + rr;
        unsigned* p = mb + (row * 2 + wc) * 4;
        p[0] = k1; p[1] = k2; p[2] = k3;
      }
    }
  }
  __syncthreads();
  if (tid < 128) {
    const unsigned* p0 = mb + (tid * 2) * 4;
    const unsigned* p1 = mb + (tid * 2 + 1) * 4;
    auto dec = [](unsigned k) -> float {
      unsigned u = k & 0xFFFFFFC0u;
      u = (u & 0x80000000u) ? (u ^ 0x80000000u) : ~u;
      return __uint_as_float(u);
    };
    float m1 = dec(p0[0]); int i1 = colB0 + (int)(p0[0] & 63u);
    float m2 = dec(p0[1]); int i2 = colB0 + (int)(p0[1] & 63u);
    float m3 = dec(p0[2]);
    rec_ins(m1, m2, m3, i1, i2, dec(p1[0]), colB0 + 64 + (int)(p1[0] & 63u));
    rec_ins(m1, m2, m3, i1, i2, dec(p1[1]), colB0 + 64 + (int)(p1[1] & 63u));
    m3 = fminf(m3, dec(p1[2]));
    Rec16 outr;
    outr.m1 = m1; outr.m2 = m2; outr.m3 = m3;
    outr.ii = (unsigned)i1 | ((unsigned)i2 << 16);
    recs[((size_t)(rowOff + rowA0 + tid) << 4) + colblk] = outr;
  }
}

// ---------------- merge 16 col-block records; classify rows -------------
__global__ __launch_bounds__(256) void k_merge(
    const Rec16* __restrict__ recs, int* __restrict__ labels,
    int4* __restrict__ pairs, int* __restrict__ scans,
    int* __restrict__ npairs, int* __restrict__ nscan) {
  int row = blockIdx.x * 256 + threadIdx.x;
  const Rec16* r = recs + ((size_t)row << 4);
  Rec16 a = r[0];
  float m1 = a.m1, m2 = a.m2, m3 = a.m3;
  int i1 = (int)(a.ii & 0xffffu), i2 = (int)(a.ii >> 16);
  #pragma unroll
  for (int cb = 1; cb < 16; ++cb) {
    Rec16 bb = r[cb];
    rec_ins(m1, m2, m3, i1, i2, bb.m1, (int)(bb.ii & 0xffffu));
    rec_ins(m1, m2, m3, i1, i2, bb.m2, (int)(bb.ii >> 16));
    m3 = fminf(m3, bb.m3);
  }
  labels[row] = i1;
  if (m2 <= m1 + SMARGIN) {
    if (m3 <= m1 + SMARGIN) {
      int s = atomicAdd(nscan, 1); scans[s] = row;
    } else {
      int p = atomicAdd(npairs, 1); pairs[p] = make_int4(row, i1, i2, 0);
    }
  }
}

// ---------------- exact rescore: 2-candidate rows ----------------
__global__ __launch_bounds__(256) void k_pairs(
    const float* __restrict__ E, const float* __restrict__ C,
    const float* __restrict__ x2, const float* __restrict__ c2,
    const int4* __restrict__ pairs, const int* __restrict__ npairs,
    int* __restrict__ labels) {
  int n = *npairs;
  int stride = gridDim.x * 256;
  for (int i = blockIdx.x * 256 + threadIdx.x; i < n; i += stride) {
    int4 p = pairs[i];
    float d1 = dist_exact(E, C, x2, c2, p.x, p.y);
    float d2 = dist_exact(E, C, x2, c2, p.x, p.z);
    labels[p.x] = (d2 < d1 || (d2 == d1 && p.z < p.y)) ? p.z : p.y;
  }
}

// ---------------- exact rescore: full-scan rows ----------------
__global__ __launch_bounds__(256) void k_scan(
    const float* __restrict__ E, const float* __restrict__ C,
    const float* __restrict__ x2, const float* __restrict__ c2,
    const int* __restrict__ scans, const int* __restrict__ nscan,
    int* __restrict__ labels) {
  __shared__ float sd[256];
  __shared__ int sj[256];
  int ns = *nscan;
  for (int s = blockIdx.x; s < ns; s += gridDim.x) {
    int row = scans[s];
    float bd = 3.4e38f; int bj = 0x7fffffff;
    for (int jj = 0; jj < 8; ++jj) {
      int j = jj * 256 + threadIdx.x;
      float d = dist_exact(E, C, x2, c2, row, j);
      if (d < bd || (d == bd && j < bj)) { bd = d; bj = j; }
    }
    sd[threadIdx.x] = bd; sj[threadIdx.x] = bj;
    __syncthreads();
    for (int st = 128; st > 0; st >>= 1) {
      if (threadIdx.x < st) {
        float od = sd[threadIdx.x + st]; int oj = sj[threadIdx.x + st];
        if (od < sd[threadIdx.x] || (od == sd[threadIdx.x] && oj < sj[threadIdx.x])) {
          sd[threadIdx.x] = od; sj[threadIdx.x] = oj;
        }
      }
      __syncthreads();
    }
    if (threadIdx.x == 0) labels[row] = sj[0];
    __syncthreads();
  }
}

// ---------------- histogram of final labels ----------------
__global__ void k_hist(const int* __restrict__ labels, int* __restrict__ cnt) {
  int i = blockIdx.x * 256 + threadIdx.x;
  if (i < NS) atomicAdd(&cnt[labels[i]], 1);
}

// ---------------- exclusive scan over 2048 counts (Blelloch) ------------
__global__ __launch_bounds__(1024) void k_prefix(const int* __restrict__ cnt,
                                                 int* __restrict__ offs,
                                                 int* __restrict__ cursors) {
  __shared__ int s[KC];
  int t = threadIdx.x;
  s[t] = cnt[t]; s[t + 1024] = cnt[t + 1024];
  int offset = 1;
  for (int d = KC >> 1; d > 0; d >>= 1) {
    __syncthreads();
    if (t < d) {
      int ai = offset * (2 * t + 1) - 1;
      int bi = offset * (2 * t + 2) - 1;
      s[bi] += s[ai];
    }
    offset <<= 1;
  }
  __syncthreads();
  if (t == 0) s[KC - 1] = 0;
  for (int d = 1; d < KC; d <<= 1) {
    offset >>= 1;
    __syncthreads();
    if (t < d) {
      int ai = offset * (2 * t + 1) - 1;
      int bi = offset * (2 * t + 2) - 1;
      int tmp = s[ai]; s[ai] = s[bi]; s[bi] += tmp;
    }
  }
  __syncthreads();
  offs[t] = s[t];               cursors[t] = s[t];
  offs[t + 1024] = s[t + 1024]; cursors[t + 1024] = s[t + 1024];
  if (t == 0) offs[KC] = NS;
}

// ---------------- scatter rows into label-sorted order (+label array) ----
__global__ void k_scatter(const int* __restrict__ labels, int* __restrict__ cursors,
                          int* __restrict__ sorted, int* __restrict__ slab,
                          float* __restrict__ out_labels) {
  int i = blockIdx.x * 256 + threadIdx.x;
  if (i < NS) {
    int lab = labels[i];
    out_labels[i] = (float)lab;
    int pos = atomicAdd(&cursors[lab], 1);
    sorted[pos] = i;
    slab[pos] = lab;
  }
}

// ---------------- balanced segmented accumulate over sorted rows --------
__global__ __launch_bounds__(256) void k_accum3(
    const float* __restrict__ E, const float* __restrict__ C,
    const int* __restrict__ sorted, const int* __restrict__ slab,
    float* __restrict__ seg, double* __restrict__ loss) {
  const int d = threadIdx.x;
  const int beg = blockIdx.x * ACHUNK;
  const int end = beg + ACHUNK;
  int cur = slab[beg];
  float sum = 0.0f;
  double lp = 0.0;
  for (int i = beg; i < end; ++i) {
    int lab = slab[i];
    if (lab != cur) {
      unsafeAtomicAdd(&seg[(size_t)cur * DD + d], sum);
      sum = 0.0f; cur = lab;
    }
    float x = E[(size_t)sorted[i] * DD + d];
    sum += x;
    float c = C[(size_t)lab * DD + d];
    float df = x - c;
    lp += (double)df * (double)df;
  }
  unsafeAtomicAdd(&seg[(size_t)cur * DD + d], sum);
  #pragma unroll
  for (int o = 32; o >= 1; o >>= 1) lp += __shfl_down(lp, o);
  __shared__ double wsum[4];
  int lane = d & 63, wv = d >> 6;
  if (lane == 0) wsum[wv] = lp;
  __syncthreads();
  if (d == 0) unsafeAtomicAdd(loss, wsum[0] + wsum[1] + wsum[2] + wsum[3]);
}

// ---------------- init seg region (= out_centers) ----------------
__global__ void k_zeroseg(float* __restrict__ segc) {
  int i = blockIdx.x * 256 + threadIdx.x;
  if (i < KC * DD) segc[i] = 0.0f;
}

// ---------------- finalize centers, counts, loss ----------------
__global__ void k_final2(const float* __restrict__ C, const int* __restrict__ counts0,
                         const int* __restrict__ offs, float* __restrict__ out_centers,
                         float* __restrict__ out_counts, float* __restrict__ out_loss,
                         const double* __restrict__ loss) {
  int i = blockIdx.x * 256 + threadIdx.x;
  if (i < KC * DD) {
    int k = i >> 8;
    float c0 = (float)counts0[k];
    float nc = c0 + (float)(offs[k + 1] - offs[k]);
    out_centers[i] = (c0 * C[i] + out_centers[i]) / nc;
  }
  if (i < KC) out_counts[i] = (float)counts0[i] + (float)(offs[i + 1] - offs[i]);
  if (i == 0) out_loss[0] = (float)(loss[0] / (double)NS);
}

extern "C" void kernel_launch(void* const* d_in, const int* in_sizes, int n_in,
                              void* d_out, int out_size, void* d_ws, size_t ws_size,
                              hipStream_t stream) {
  const float* E = (const float*)d_in[0];
  const float* C = (const float*)d_in[1];
  const int* counts0 = (const int*)d_in[2];

  float* out = (float*)d_out;
  float* out_labels  = out;                     // [NS]
  float* out_loss    = out + NS;                // [1]
  float* out_centers = out + NS + 1;            // [KC*DD] (doubles as seg acc)
  float* out_counts  = out + NS + 1 + KC * DD;  // [KC]

  char* ws = (char*)d_ws;
  size_t o = 0;
  auto alloc = [&](size_t bytes) -> void* {
    void* p = ws + o;
    o += (bytes + 255) & ~(size_t)255;
    return p;
  };
  double* loss_acc = (double*)alloc(256);  // loss @0, npairs @16, nscan @20
  int* npairs = (int*)((char*)loss_acc + 16);
  int* nscan  = (int*)((char*)loss_acc + 20);
  int*   labels  = (int*)alloc(4 * (size_t)NS);
  float* x2      = (float*)alloc(4 * (size_t)NS);
  float* c2      = (float*)alloc(4 * KC);
  int*   cnt     = (int*)alloc(4 * KC);
  int*   offs    = (int*)alloc(4 * (KC + 1));
  int*   cursors = (int*)alloc(4 * KC);
  int*   sorted  = (int*)alloc(4 * (size_t)NS);
  int*   slab    = (int*)alloc(4 * (size_t)NS);
  unsigned short* CX = (unsigned short*)alloc(2 * (size_t)KC * 256);
  Rec16* recs    = (Rec16*)alloc(sizeof(Rec16) * (size_t)NS * 16);
  int4*  pairs   = (int4*)alloc(16 * (size_t)NS);
  int*   scans   = (int*)alloc(4 * (size_t)NS);

  // EX chunk (rows of 512 fp16 = 1KB): full NS if it fits, else halve
  size_t avail = (ws_size > o) ? (ws_size - o) : 0;
  int CH = NS;
  while (CH > 2048 && (size_t)CH * 1024 > avail) CH >>= 1;
  unsigned short* EX = (unsigned short*)alloc((size_t)CH * 1024);
  int NCH = NS / CH;

  hipLaunchKernelGGL(k_init, dim3(8), dim3(256), 0, stream,
                     cnt, loss_acc, npairs, nscan);
  hipLaunchKernelGGL(k_zeroseg, dim3((KC * DD + 255) / 256), dim3(256), 0, stream,
                     out_centers);
  hipLaunchKernelGGL(k_rownorm, dim3(NS * 8 / 256), dim3(256), 0, stream, E, x2, NS);
  hipLaunchKernelGGL(k_rownorm, dim3(KC * 8 / 256), dim3(256), 0, stream, C, c2, KC);
  hipLaunchKernelGGL(k_split16c, dim3(KC * 32 / 256), dim3(256), 0, stream,
                     C, CX, KC * 32);

  for (int ch = 0; ch < NCH; ++ch) {
    hipLaunchKernelGGL(k_split16, dim3(CH * 32 / 256), dim3(256), 0, stream,
                       E + (size_t)ch * CH * DD, EX, CH * 32);
    hipLaunchKernelGGL(k_screen16, dim3((CH / 128) * 16), dim3(256), 0, stream,
                       EX, CX, c2, recs, ch * CH);
  }

  hipLaunchKernelGGL(k_merge, dim3(NS / 256), dim3(256), 0, stream,
                     recs, labels, pairs, scans, npairs, nscan);
  hipLaunchKernelGGL(k_pairs, dim3(64), dim3(256), 0, stream,
                     E, C, x2, c2, pairs, npairs, labels);
  hipLaunchKernelGGL(k_scan, dim3(128), dim3(256), 0, stream,
                     E, C, x2, c2, scans, nscan, labels);
  hipLaunchKernelGGL(k_hist, dim3(NS / 256), dim3(256), 0, stream, labels, cnt);
  hipLaunchKernelGGL(k_prefix, dim3(1), dim3(1024), 0, stream, cnt, offs, cursors);
  hipLaunchKernelGGL(k_scatter, dim3(NS / 256), dim3(256), 0, stream,
                     labels, cursors, sorted, slab, out_labels);
  hipLaunchKernelGGL(k_accum3, dim3(NS / ACHUNK), dim3(256), 0, stream,
                     E, C, sorted, slab, out_centers, loss_acc);
  hipLaunchKernelGGL(k_final2, dim3((KC * DD + 255) / 256), dim3(256), 0, stream,
                     C, counts0, offs, out_centers, out_counts, out_loss, loss_acc);
}

// Round 12
// 704.578 us; speedup vs baseline: 1.4195x; 1.2427x over previous
//
#include <hip/hip_runtime.h>

typedef _Float16 f16x8 __attribute__((ext_vector_type(8)));
typedef float f32x4 __attribute__((ext_vector_type(4)));

#define NS 131072
#define KC 2048
#define DD 256
#define SMARGIN 0.12f
#define ACHUNK 128

struct Rec16 { float m1, m2, m3; unsigned ii; };  // ii = i1 | (i2<<16)

// ---------------- helpers ----------------
__device__ __forceinline__ unsigned umin_(unsigned a, unsigned b) { return a < b ? a : b; }
__device__ __forceinline__ unsigned umax_(unsigned a, unsigned b) { return a > b ? a : b; }

__device__ __forceinline__ void async16(void* lds, const void* g) {
  __builtin_amdgcn_global_load_lds(
      (const __attribute__((address_space(1))) unsigned*)g,
      (__attribute__((address_space(3))) unsigned*)lds, 16, 0, 0);
}

__device__ __forceinline__ void rec_ins(float& m1, float& m2, float& m3,
                                        int& i1, int& i2, float q, int i) {
  if (q < m1 || (q == m1 && i < i1)) {
    m3 = m2; m2 = m1; i2 = i1; m1 = q; i1 = i;
  } else if (q < m2 || (q == m2 && i < i2)) {
    m3 = m2; m2 = q; i2 = i;
  } else if (q < m3) {
    m3 = q;
  }
}

// exact fp32 distance: bit-identical to the verified round-2/3 chain
__device__ __forceinline__ float dist_exact(const float* __restrict__ E,
                                            const float* __restrict__ C,
                                            const float* __restrict__ x2,
                                            const float* __restrict__ c2,
                                            int row, int j) {
  const float* e = E + (size_t)row * DD;
  const float* c = C + (size_t)j * DD;
  float acc = 0.0f;
  #pragma unroll 8
  for (int k = 0; k < DD; ++k) acc = fmaf(e[k], c[k], acc);
  return __fadd_rn(__fsub_rn(x2[row], __fmul_rn(2.0f, acc)), c2[j]);
}

// ---------------- init: zero seg (= out_centers), cnt, counters ----------
__global__ void k_init(float* __restrict__ segc, int* __restrict__ cnt,
                       double* __restrict__ loss, int* __restrict__ npairs,
                       int* __restrict__ nscan) {
  int i = blockIdx.x * 256 + threadIdx.x;
  if (i < KC * DD) segc[i] = 0.0f;
  if (i < KC) cnt[i] = 0;
  if (i == 0) { *loss = 0.0; *npairs = 0; *nscan = 0; }
}

// ---------------- row norms, numpy-pairwise-exact fp32 (proven) ----------
__global__ __launch_bounds__(256) void k_rownorm(const float* __restrict__ A,
                                                 float* __restrict__ out,
                                                 int nrows) {
  int g = blockIdx.x * 256 + threadIdx.x;
  int row = g >> 3;
  int l = g & 7;
  if (row >= nrows) return;
  const float* p = A + (size_t)row * DD;
  float halfs[2];
  #pragma unroll
  for (int h = 0; h < 2; ++h) {
    const float* q = p + h * 128;
    float x = q[l];
    float r = __fmul_rn(x, x);
    #pragma unroll
    for (int i = 8; i < 128; i += 8) {
      float y = q[i + l];
      r = __fadd_rn(r, __fmul_rn(y, y));
    }
    float t = __fadd_rn(r, __shfl_xor(r, 1));
    t = __fadd_rn(t, __shfl_xor(t, 2));
    t = __fadd_rn(t, __shfl_xor(t, 4));
    halfs[h] = t;
  }
  if (l == 0) out[row] = __fadd_rn(halfs[0], halfs[1]);
}

// ---------------- f32 -> fp16 hi (row of 256) ----------------
__global__ __launch_bounds__(256) void k_split16h(const float* __restrict__ src,
                                                  unsigned short* __restrict__ dst,
                                                  int n32) {
  int g = blockIdx.x * 256 + threadIdx.x;
  if (g >= n32) return;
  int row = g >> 5, seg = g & 31;
  const float4* s = (const float4*)(src + (size_t)row * DD + seg * 8);
  float4 v0 = s[0], v1 = s[1];
  float xs[8] = {v0.x, v0.y, v0.z, v0.w, v1.x, v1.y, v1.z, v1.w};
  unsigned short hv[8];
  #pragma unroll
  for (int i = 0; i < 8; ++i) {
    union { _Float16 h; unsigned short u; } ch;
    ch.h = (_Float16)xs[i];
    hv[i] = ch.u;
  }
  *(ulonglong2*)(dst + (size_t)row * 256 + seg * 8) = *(ulonglong2*)hv;
}

// ---------------- MFMA screening GEMM + per-row approx top-3 ------------
// Pure fp16-hi screen: dot = hi_x · hi_c over K=256 (err std ~0.010 on the
// distance; SMARGIN = 0.12 ≈ 8.5 sigma of the pairwise error difference).
// 128x128 tile, BK=64, 4 waves (2x2), 2-phase double-buffered LDS, 4 slabs.
__global__ __launch_bounds__(256, 2) void k_screen16(
    const unsigned short* __restrict__ EX, const unsigned short* __restrict__ CX,
    const float* __restrict__ c2, Rec16* __restrict__ recs, int rowOff) {
  __shared__ char smem[65536];  // 2 bufs x (A 16K | B 16K)

  const int nwg = gridDim.x;
  const int b = blockIdx.x;
  const int swzb = (b & 7) * (nwg >> 3) + (b >> 3);   // bijective: nwg % 8 == 0
  const int colblk = swzb & 15, rowblk = swzb >> 4;

  const int tid = threadIdx.x;
  const int wave = tid >> 6, lane = tid & 63;
  const int ln15 = lane & 15, ln4 = lane >> 4;
  const int wr = wave >> 1, wc = wave & 1;
  const int rowA0 = rowblk * 128;
  const int colB0 = colblk * 128;
  const int rsw = ((lane & 7) ^ (lane >> 3)) << 3;  // src pre-swizzle (elems)

  // hoisted global staging pointers (per t-round of 8 rows)
  const unsigned short* pA[4];
  const unsigned short* pB[4];
  {
    size_t ra = (size_t)(rowA0 + wave * 32 + (lane >> 3)) * 256 + rsw;
    size_t rb = (size_t)(colB0 + wave * 32 + (lane >> 3)) * 256 + rsw;
    #pragma unroll
    for (int t = 0; t < 4; ++t) {
      pA[t] = EX + ra + t * 2048;   // t*8 rows x 256
      pB[t] = CX + rb + t * 2048;
    }
  }
  // wave-uniform LDS staging bases
  char* ldsA = smem + wave * 4096;
  char* ldsB = smem + 16384 + wave * 4096;
  // hoisted swizzled ds_read addresses [ks][frag]
  const char* aaddr[2][4];
  const char* baddr[2][4];
  #pragma unroll
  for (int ks = 0; ks < 2; ++ks) {
    int sz = ((ks * 4 + ln4) ^ (ln15 & 7)) << 4;
    #pragma unroll
    for (int m = 0; m < 4; ++m)
      aaddr[ks][m] = smem + (wr * 64 + m * 16 + ln15) * 128 + sz;
    #pragma unroll
    for (int n = 0; n < 4; ++n)
      baddr[ks][n] = smem + 16384 + (wc * 64 + n * 16 + ln15) * 128 + sz;
  }

  f32x4 acc[4][4];
  #pragma unroll
  for (int m = 0; m < 4; ++m)
    #pragma unroll
    for (int n = 0; n < 4; ++n) acc[m][n] = (f32x4){0.f, 0.f, 0.f, 0.f};

#define STAGE(s) {                                                        \
    const int _buf = (s) & 1;                                             \
    const int _k = (s) * 64;                                              \
    _Pragma("unroll")                                                     \
    for (int t = 0; t < 4; ++t) {                                         \
      async16(ldsA + _buf * 32768 + t * 1024, pA[t] + _k);                \
      async16(ldsB + _buf * 32768 + t * 1024, pB[t] + _k);                \
    } }

#define COMPUTE(s) {                                                      \
    const int _bo = ((s) & 1) * 32768;                                    \
    _Pragma("unroll")                                                     \
    for (int ks = 0; ks < 2; ++ks) {                                      \
      f16x8 a[4], bb[4];                                                  \
      _Pragma("unroll")                                                   \
      for (int m = 0; m < 4; ++m)                                         \
        a[m] = *(const f16x8*)(aaddr[ks][m] + _bo);                       \
      _Pragma("unroll")                                                   \
      for (int n = 0; n < 4; ++n)                                         \
        bb[n] = *(const f16x8*)(baddr[ks][n] + _bo);                      \
      _Pragma("unroll")                                                   \
      for (int m = 0; m < 4; ++m)                                         \
        _Pragma("unroll")                                                 \
        for (int n = 0; n < 4; ++n)                                       \
          acc[m][n] = __builtin_amdgcn_mfma_f32_16x16x32_f16(             \
              a[m], bb[n], acc[m][n], 0, 0, 0);                           \
    } }

  STAGE(0);
  __syncthreads();
  #pragma unroll
  for (int s = 0; s < 4; ++s) {
    if (s < 3) STAGE(s + 1);
    COMPUTE(s);
    __syncthreads();
  }
#undef STAGE
#undef COMPUTE

  // ---- branchless epilogue: sortable-u32 keys, col packed in low 6 bits
  float c2v[4];
  #pragma unroll
  for (int n = 0; n < 4; ++n) c2v[n] = c2[colB0 + wc * 64 + n * 16 + ln15];

  unsigned* mb = (unsigned*)smem;  // [128 rows][2 wc][4 words]
  #pragma unroll
  for (int m = 0; m < 4; ++m) {
    #pragma unroll
    for (int rr = 0; rr < 4; ++rr) {
      unsigned k1 = 0xFFFFFFFFu, k2 = 0xFFFFFFFFu, k3 = 0xFFFFFFFFu;
      #pragma unroll
      for (int n = 0; n < 4; ++n) {
        float q = fmaf(-2.0f, acc[m][n][rr], c2v[n]);
        unsigned u = __float_as_uint(q);
        unsigned msk = 0x80000000u | (unsigned)((int)u >> 31);
        unsigned key = ((u ^ msk) & 0xFFFFFFC0u) | (unsigned)(n * 16 + ln15);
        unsigned t1 = umax_(k1, key);
        k1 = umin_(k1, key);
        unsigned t2 = umax_(k2, t1);
        k2 = umin_(k2, t1);
        k3 = umin_(k3, t2);
      }
      #pragma unroll
      for (int sh = 1; sh <= 8; sh <<= 1) {
        unsigned o1 = (unsigned)__shfl_xor((int)k1, sh);
        unsigned o2 = (unsigned)__shfl_xor((int)k2, sh);
        unsigned o3 = (unsigned)__shfl_xor((int)k3, sh);
        unsigned mm = umax_(k1, o1);
        k1 = umin_(k1, o1);
        unsigned tt = umin_(k2, o2);
        k2 = umin_(mm, tt);
        k3 = umin_(umin_(k3, o3), umax_(mm, tt));
      }
      if (ln15 == 0) {
        int row = wr * 64 + m * 16 + ln4 * 4 + rr;
        unsigned* p = mb + (row * 2 + wc) * 4;
        p[0] = k1; p[1] = k2; p[2] = k3;
      }
    }
  }
  __syncthreads();
  if (tid < 128) {
    const unsigned* p0 = mb + (tid * 2) * 4;
    const unsigned* p1 = mb + (tid * 2 + 1) * 4;
    auto dec = [](unsigned k) -> float {
      unsigned u = k & 0xFFFFFFC0u;
      u = (u & 0x80000000u) ? (u ^ 0x80000000u) : ~u;
      return __uint_as_float(u);
    };
    float m1 = dec(p0[0]); int i1 = colB0 + (int)(p0[0] & 63u);
    float m2 = dec(p0[1]); int i2 = colB0 + (int)(p0[1] & 63u);
    float m3 = dec(p0[2]);
    rec_ins(m1, m2, m3, i1, i2, dec(p1[0]), colB0 + 64 + (int)(p1[0] & 63u));
    rec_ins(m1, m2, m3, i1, i2, dec(p1[1]), colB0 + 64 + (int)(p1[1] & 63u));
    m3 = fminf(m3, dec(p1[2]));
    Rec16 outr;
    outr.m1 = m1; outr.m2 = m2; outr.m3 = m3;
    outr.ii = (unsigned)i1 | ((unsigned)i2 << 16);
    recs[((size_t)(rowOff + rowA0 + tid) << 4) + colblk] = outr;
  }
}

// ---------------- merge 16 col-block records; classify rows -------------
__global__ __launch_bounds__(256) void k_merge(
    const Rec16* __restrict__ recs, int* __restrict__ labels,
    int4* __restrict__ pairs, int* __restrict__ scans,
    int* __restrict__ npairs, int* __restrict__ nscan) {
  int row = blockIdx.x * 256 + threadIdx.x;
  const Rec16* r = recs + ((size_t)row << 4);
  Rec16 a = r[0];
  float m1 = a.m1, m2 = a.m2, m3 = a.m3;
  int i1 = (int)(a.ii & 0xffffu), i2 = (int)(a.ii >> 16);
  #pragma unroll
  for (int cb = 1; cb < 16; ++cb) {
    Rec16 bb = r[cb];
    rec_ins(m1, m2, m3, i1, i2, bb.m1, (int)(bb.ii & 0xffffu));
    rec_ins(m1, m2, m3, i1, i2, bb.m2, (int)(bb.ii >> 16));
    m3 = fminf(m3, bb.m3);
  }
  labels[row] = i1;
  if (m2 <= m1 + SMARGIN) {
    if (m3 <= m1 + SMARGIN) {
      int s = atomicAdd(nscan, 1); scans[s] = row;
    } else {
      int p = atomicAdd(npairs, 1); pairs[p] = make_int4(row, i1, i2, 0);
    }
  }
}

// ---------------- exact rescore: 2-candidate rows ----------------
__global__ __launch_bounds__(256) void k_pairs(
    const float* __restrict__ E, const float* __restrict__ C,
    const float* __restrict__ x2, const float* __restrict__ c2,
    const int4* __restrict__ pairs, const int* __restrict__ npairs,
    int* __restrict__ labels) {
  int n = *npairs;
  int stride = gridDim.x * 256;
  for (int i = blockIdx.x * 256 + threadIdx.x; i < n; i += stride) {
    int4 p = pairs[i];
    float d1 = dist_exact(E, C, x2, c2, p.x, p.y);
    float d2 = dist_exact(E, C, x2, c2, p.x, p.z);
    labels[p.x] = (d2 < d1 || (d2 == d1 && p.z < p.y)) ? p.z : p.y;
  }
}

// ---------------- exact rescore: full-scan rows ----------------
__global__ __launch_bounds__(256) void k_scan(
    const float* __restrict__ E, const float* __restrict__ C,
    const float* __restrict__ x2, const float* __restrict__ c2,
    const int* __restrict__ scans, const int* __restrict__ nscan,
    int* __restrict__ labels) {
  __shared__ float sd[256];
  __shared__ int sj[256];
  int ns = *nscan;
  for (int s = blockIdx.x; s < ns; s += gridDim.x) {
    int row = scans[s];
    float bd = 3.4e38f; int bj = 0x7fffffff;
    for (int jj = 0; jj < 8; ++jj) {
      int j = jj * 256 + threadIdx.x;
      float d = dist_exact(E, C, x2, c2, row, j);
      if (d < bd || (d == bd && j < bj)) { bd = d; bj = j; }
    }
    sd[threadIdx.x] = bd; sj[threadIdx.x] = bj;
    __syncthreads();
    for (int st = 128; st > 0; st >>= 1) {
      if (threadIdx.x < st) {
        float od = sd[threadIdx.x + st]; int oj = sj[threadIdx.x + st];
        if (od < sd[threadIdx.x] || (od == sd[threadIdx.x] && oj < sj[threadIdx.x])) {
          sd[threadIdx.x] = od; sj[threadIdx.x] = oj;
        }
      }
      __syncthreads();
    }
    if (threadIdx.x == 0) labels[row] = sj[0];
    __syncthreads();
  }
}

// ---------------- histogram of final labels ----------------
__global__ void k_hist(const int* __restrict__ labels, int* __restrict__ cnt) {
  int i = blockIdx.x * 256 + threadIdx.x;
  if (i < NS) atomicAdd(&cnt[labels[i]], 1);
}

// ---------------- exclusive scan over 2048 counts (Blelloch) ------------
__global__ __launch_bounds__(1024) void k_prefix(const int* __restrict__ cnt,
                                                 int* __restrict__ offs,
                                                 int* __restrict__ cursors) {
  __shared__ int s[KC];
  int t = threadIdx.x;
  s[t] = cnt[t]; s[t + 1024] = cnt[t + 1024];
  int offset = 1;
  for (int d = KC >> 1; d > 0; d >>= 1) {
    __syncthreads();
    if (t < d) {
      int ai = offset * (2 * t + 1) - 1;
      int bi = offset * (2 * t + 2) - 1;
      s[bi] += s[ai];
    }
    offset <<= 1;
  }
  __syncthreads();
  if (t == 0) s[KC - 1] = 0;
  for (int d = 1; d < KC; d <<= 1) {
    offset >>= 1;
    __syncthreads();
    if (t < d) {
      int ai = offset * (2 * t + 1) - 1;
      int bi = offset * (2 * t + 2) - 1;
      int tmp = s[ai]; s[ai] = s[bi]; s[bi] += tmp;
    }
  }
  __syncthreads();
  offs[t] = s[t];               cursors[t] = s[t];
  offs[t + 1024] = s[t + 1024]; cursors[t + 1024] = s[t + 1024];
  if (t == 0) offs[KC] = NS;
}

// ---------------- scatter rows into label-sorted order (+label array) ----
__global__ void k_scatter(const int* __restrict__ labels, int* __restrict__ cursors,
                          int* __restrict__ sorted, int* __restrict__ slab,
                          float* __restrict__ out_labels) {
  int i = blockIdx.x * 256 + threadIdx.x;
  if (i < NS) {
    int lab = labels[i];
    out_labels[i] = (float)lab;
    int pos = atomicAdd(&cursors[lab], 1);
    sorted[pos] = i;
    slab[pos] = lab;
  }
}

// ---------------- balanced segmented accumulate over sorted rows --------
__global__ __launch_bounds__(256) void k_accum3(
    const float* __restrict__ E, const float* __restrict__ C,
    const int* __restrict__ sorted, const int* __restrict__ slab,
    float* __restrict__ seg, double* __restrict__ loss) {
  const int d = threadIdx.x;
  const int beg = blockIdx.x * ACHUNK;
  const int end = beg + ACHUNK;
  int cur = slab[beg];
  float sum = 0.0f;
  double lp = 0.0;
  for (int i = beg; i < end; ++i) {
    int lab = slab[i];
    if (lab != cur) {
      unsafeAtomicAdd(&seg[(size_t)cur * DD + d], sum);
      sum = 0.0f; cur = lab;
    }
    float x = E[(size_t)sorted[i] * DD + d];
    sum += x;
    float c = C[(size_t)lab * DD + d];
    float df = x - c;
    lp += (double)df * (double)df;
  }
  unsafeAtomicAdd(&seg[(size_t)cur * DD + d], sum);
  #pragma unroll
  for (int o = 32; o >= 1; o >>= 1) lp += __shfl_down(lp, o);
  __shared__ double wsum[4];
  int lane = d & 63, wv = d >> 6;
  if (lane == 0) wsum[wv] = lp;
  __syncthreads();
  if (d == 0) unsafeAtomicAdd(loss, wsum[0] + wsum[1] + wsum[2] + wsum[3]);
}

// ---------------- finalize centers, counts, loss ----------------
__global__ void k_final2(const float* __restrict__ C, const int* __restrict__ counts0,
                         const int* __restrict__ offs, float* __restrict__ out_centers,
                         float* __restrict__ out_counts, float* __restrict__ out_loss,
                         const double* __restrict__ loss) {
  int i = blockIdx.x * 256 + threadIdx.x;
  if (i < KC * DD) {
    int k = i >> 8;
    float c0 = (float)counts0[k];
    float nc = c0 + (float)(offs[k + 1] - offs[k]);
    out_centers[i] = (c0 * C[i] + out_centers[i]) / nc;
  }
  if (i < KC) out_counts[i] = (float)counts0[i] + (float)(offs[i + 1] - offs[i]);
  if (i == 0) out_loss[0] = (float)(loss[0] / (double)NS);
}

extern "C" void kernel_launch(void* const* d_in, const int* in_sizes, int n_in,
                              void* d_out, int out_size, void* d_ws, size_t ws_size,
                              hipStream_t stream) {
  const float* E = (const float*)d_in[0];
  const float* C = (const float*)d_in[1];
  const int* counts0 = (const int*)d_in[2];

  float* out = (float*)d_out;
  float* out_labels  = out;                     // [NS]
  float* out_loss    = out + NS;                // [1]
  float* out_centers = out + NS + 1;            // [KC*DD] (doubles as seg acc)
  float* out_counts  = out + NS + 1 + KC * DD;  // [KC]

  char* ws = (char*)d_ws;
  size_t o = 0;
  auto alloc = [&](size_t bytes) -> void* {
    void* p = ws + o;
    o += (bytes + 255) & ~(size_t)255;
    return p;
  };
  double* loss_acc = (double*)alloc(256);  // loss @0, npairs @16, nscan @20
  int* npairs = (int*)((char*)loss_acc + 16);
  int* nscan  = (int*)((char*)loss_acc + 20);
  int*   labels  = (int*)alloc(4 * (size_t)NS);
  float* x2      = (float*)alloc(4 * (size_t)NS);
  float* c2      = (float*)alloc(4 * KC);
  int*   cnt     = (int*)alloc(4 * KC);
  int*   offs    = (int*)alloc(4 * (KC + 1));
  int*   cursors = (int*)alloc(4 * KC);
  int*   sorted  = (int*)alloc(4 * (size_t)NS);
  int*   slab    = (int*)alloc(4 * (size_t)NS);
  unsigned short* CX = (unsigned short*)alloc(2 * (size_t)KC * 256);
  Rec16* recs    = (Rec16*)alloc(sizeof(Rec16) * (size_t)NS * 16);
  int4*  pairs   = (int4*)alloc(16 * (size_t)NS);
  int*   scans   = (int*)alloc(4 * (size_t)NS);

  // EX chunk (rows of 256 fp16 = 512 B): full NS if it fits, else halve
  size_t avail = (ws_size > o) ? (ws_size - o) : 0;
  int CH = NS;
  while (CH > 2048 && (size_t)CH * 512 > avail) CH >>= 1;
  unsigned short* EX = (unsigned short*)alloc((size_t)CH * 512);
  int NCH = NS / CH;

  hipLaunchKernelGGL(k_init, dim3((KC * DD + 255) / 256), dim3(256), 0, stream,
                     out_centers, cnt, loss_acc, npairs, nscan);
  hipLaunchKernelGGL(k_rownorm, dim3(NS * 8 / 256), dim3(256), 0, stream, E, x2, NS);
  hipLaunchKernelGGL(k_rownorm, dim3(KC * 8 / 256), dim3(256), 0, stream, C, c2, KC);
  hipLaunchKernelGGL(k_split16h, dim3(KC * 32 / 256), dim3(256), 0, stream,
                     C, CX, KC * 32);

  for (int ch = 0; ch < NCH; ++ch) {
    hipLaunchKernelGGL(k_split16h, dim3(CH * 32 / 256), dim3(256), 0, stream,
                       E + (size_t)ch * CH * DD, EX, CH * 32);
    hipLaunchKernelGGL(k_screen16, dim3((CH / 128) * 16), dim3(256), 0, stream,
                       EX, CX, c2, recs, ch * CH);
  }

  hipLaunchKernelGGL(k_merge, dim3(NS / 256), dim3(256), 0, stream,
                     recs, labels, pairs, scans, npairs, nscan);
  hipLaunchKernelGGL(k_pairs, dim3(64), dim3(256), 0, stream,
                     E, C, x2, c2, pairs, npairs, labels);
  hipLaunchKernelGGL(k_scan, dim3(128), dim3(256), 0, stream,
                     E, C, x2, c2, scans, nscan, labels);
  hipLaunchKernelGGL(k_hist, dim3(NS / 256), dim3(256), 0, stream, labels, cnt);
  hipLaunchKernelGGL(k_prefix, dim3(1), dim3(1024), 0, stream, cnt, offs, cursors);
  hipLaunchKernelGGL(k_scatter, dim3(NS / 256), dim3(256), 0, stream,
                     labels, cursors, sorted, slab, out_labels);
  hipLaunchKernelGGL(k_accum3, dim3(NS / ACHUNK), dim3(256), 0, stream,
                     E, C, sorted, slab, out_centers, loss_acc);
  hipLaunchKernelGGL(k_final2, dim3((KC * DD + 255) / 256), dim3(256), 0, stream,
                     C, counts0, offs, out_centers, out_counts, out_loss, loss_acc);
}

// Round 13
// 671.711 us; speedup vs baseline: 1.4890x; 1.0489x over previous
//
#include <hip/hip_runtime.h>

typedef _Float16 f16x8 __attribute__((ext_vector_type(8)));
typedef float f32x4 __attribute__((ext_vector_type(4)));

#define NS 131072
#define KC 2048
#define DD 256
#define SMARGIN 0.12f
#define ACHUNK 128

struct Rec16 { float m1, m2, m3; unsigned ii; };  // ii = i1 | (i2<<16)

// ---------------- helpers ----------------
__device__ __forceinline__ unsigned umin_(unsigned a, unsigned b) { return a < b ? a : b; }
__device__ __forceinline__ unsigned umax_(unsigned a, unsigned b) { return a > b ? a : b; }

__device__ __forceinline__ void async16(void* lds, const void* g) {
  __builtin_amdgcn_global_load_lds(
      (const __attribute__((address_space(1))) unsigned*)g,
      (__attribute__((address_space(3))) unsigned*)lds, 16, 0, 0);
}

__device__ __forceinline__ void rec_ins(float& m1, float& m2, float& m3,
                                        int& i1, int& i2, float q, int i) {
  if (q < m1 || (q == m1 && i < i1)) {
    m3 = m2; m2 = m1; i2 = i1; m1 = q; i1 = i;
  } else if (q < m2 || (q == m2 && i < i2)) {
    m3 = m2; m2 = q; i2 = i;
  } else if (q < m3) {
    m3 = q;
  }
}

// exact fp32 distance: bit-identical to the verified round-2/3 chain
__device__ __forceinline__ float dist_exact(const float* __restrict__ E,
                                            const float* __restrict__ C,
                                            const float* __restrict__ x2,
                                            const float* __restrict__ c2,
                                            int row, int j) {
  const float* e = E + (size_t)row * DD;
  const float* c = C + (size_t)j * DD;
  float acc = 0.0f;
  #pragma unroll 8
  for (int k = 0; k < DD; ++k) acc = fmaf(e[k], c[k], acc);
  return __fadd_rn(__fsub_rn(x2[row], __fmul_rn(2.0f, acc)), c2[j]);
}

// ---------------- fused prep: numpy-exact rownorm + fp16 convert --------
// 32 rows per block; float chain bit-identical to the proven k_rownorm.
__global__ __launch_bounds__(256) void k_prep(const float* __restrict__ A,
                                              float* __restrict__ out,
                                              unsigned short* __restrict__ AX) {
  __shared__ unsigned short sx[32 * 256];  // 16 KB
  const int r = threadIdx.x >> 3, l = threadIdx.x & 7;
  const int row = blockIdx.x * 32 + r;
  const float* p = A + (size_t)row * DD;
  float halfs[2];
  #pragma unroll
  for (int h = 0; h < 2; ++h) {
    const float* q = p + h * 128;
    float x = q[l];
    { union { _Float16 hf; unsigned short u; } c; c.hf = (_Float16)x;
      sx[r * 256 + h * 128 + l] = c.u; }
    float racc = __fmul_rn(x, x);
    #pragma unroll
    for (int i = 8; i < 128; i += 8) {
      float y = q[i + l];
      { union { _Float16 hf; unsigned short u; } c; c.hf = (_Float16)y;
        sx[r * 256 + h * 128 + i + l] = c.u; }
      racc = __fadd_rn(racc, __fmul_rn(y, y));
    }
    float t = __fadd_rn(racc, __shfl_xor(racc, 1));
    t = __fadd_rn(t, __shfl_xor(t, 2));
    t = __fadd_rn(t, __shfl_xor(t, 4));
    halfs[h] = t;
  }
  if (l == 0) out[row] = __fadd_rn(halfs[0], halfs[1]);
  __syncthreads();
  const ulonglong2* s = (const ulonglong2*)sx;
  ulonglong2* d = (ulonglong2*)(AX + (size_t)blockIdx.x * 32 * 256);
  #pragma unroll
  for (int i = 0; i < 4; ++i) d[threadIdx.x + i * 256] = s[threadIdx.x + i * 256];
}

// ---------------- MFMA screening GEMM + per-row approx top-3 ------------
// Pure fp16-hi screen, K=256, 128x128 tile, BK=64, 4 waves (2x2).
// Counted-vmcnt 2-buffer pipeline: never drain to vmcnt(0) mid-loop (T4).
__global__ __launch_bounds__(256, 2) void k_screen16(
    const unsigned short* __restrict__ EX, const unsigned short* __restrict__ CX,
    const float* __restrict__ c2, Rec16* __restrict__ recs, int rowOff) {
  __shared__ char smem[65536];  // 2 bufs x (A 16K | B 16K)

  const int nwg = gridDim.x;
  const int b = blockIdx.x;
  const int swzb = (b & 7) * (nwg >> 3) + (b >> 3);   // bijective: nwg % 8 == 0
  const int colblk = swzb & 15, rowblk = swzb >> 4;

  const int tid = threadIdx.x;
  const int wave = tid >> 6, lane = tid & 63;
  const int ln15 = lane & 15, ln4 = lane >> 4;
  const int wr = wave >> 1, wc = wave & 1;
  const int rowA0 = rowblk * 128;
  const int colB0 = colblk * 128;
  const int rsw = ((lane & 7) ^ (lane >> 3)) << 3;  // src pre-swizzle (elems)

  const unsigned short* pA[4];
  const unsigned short* pB[4];
  {
    size_t ra = (size_t)(rowA0 + wave * 32 + (lane >> 3)) * 256 + rsw;
    size_t rb = (size_t)(colB0 + wave * 32 + (lane >> 3)) * 256 + rsw;
    #pragma unroll
    for (int t = 0; t < 4; ++t) {
      pA[t] = EX + ra + t * 2048;
      pB[t] = CX + rb + t * 2048;
    }
  }
  char* ldsA = smem + wave * 4096;
  char* ldsB = smem + 16384 + wave * 4096;
  const char* aaddr[2][4];
  const char* baddr[2][4];
  #pragma unroll
  for (int ks = 0; ks < 2; ++ks) {
    int sz = ((ks * 4 + ln4) ^ (ln15 & 7)) << 4;
    #pragma unroll
    for (int m = 0; m < 4; ++m)
      aaddr[ks][m] = smem + (wr * 64 + m * 16 + ln15) * 128 + sz;
    #pragma unroll
    for (int n = 0; n < 4; ++n)
      baddr[ks][n] = smem + 16384 + (wc * 64 + n * 16 + ln15) * 128 + sz;
  }

  f32x4 acc[4][4];
  #pragma unroll
  for (int m = 0; m < 4; ++m)
    #pragma unroll
    for (int n = 0; n < 4; ++n) acc[m][n] = (f32x4){0.f, 0.f, 0.f, 0.f};

#define VMW8() do { asm volatile("s_waitcnt vmcnt(8)" ::: "memory"); \
                    __builtin_amdgcn_sched_barrier(0); } while (0)
#define VMW0() do { asm volatile("s_waitcnt vmcnt(0)" ::: "memory"); \
                    __builtin_amdgcn_sched_barrier(0); } while (0)
#define BAR() __builtin_amdgcn_s_barrier();

#define STAGE(s) {                                                        \
    const int _buf = (s) & 1;                                             \
    const int _k = (s) * 64;                                              \
    _Pragma("unroll")                                                     \
    for (int t = 0; t < 4; ++t) {                                         \
      async16(ldsA + _buf * 32768 + t * 1024, pA[t] + _k);                \
      async16(ldsB + _buf * 32768 + t * 1024, pB[t] + _k);                \
    } }

#define COMPUTE(s) {                                                      \
    const int _bo = ((s) & 1) * 32768;                                    \
    _Pragma("unroll")                                                     \
    for (int ks = 0; ks < 2; ++ks) {                                      \
      f16x8 a[4], bb[4];                                                  \
      _Pragma("unroll")                                                   \
      for (int m = 0; m < 4; ++m)                                         \
        a[m] = *(const f16x8*)(aaddr[ks][m] + _bo);                       \
      _Pragma("unroll")                                                   \
      for (int n = 0; n < 4; ++n)                                         \
        bb[n] = *(const f16x8*)(baddr[ks][n] + _bo);                      \
      _Pragma("unroll")                                                   \
      for (int m = 0; m < 4; ++m)                                         \
        _Pragma("unroll")                                                 \
        for (int n = 0; n < 4; ++n)                                       \
          acc[m][n] = __builtin_amdgcn_mfma_f32_16x16x32_f16(             \
              a[m], bb[n], acc[m][n], 0, 0, 0);                           \
    } }

  // pipeline: 2 slabs in flight; wait only for the slab we consume
  STAGE(0); STAGE(1);
  VMW8(); BAR(); COMPUTE(0); BAR(); STAGE(2);
  VMW8(); BAR(); COMPUTE(1); BAR(); STAGE(3);
  VMW8(); BAR(); COMPUTE(2); BAR();
  VMW0(); BAR(); COMPUTE(3);
#undef STAGE
#undef COMPUTE

  __syncthreads();

  // ---- branchless epilogue: sortable-u32 keys, col packed in low 6 bits
  float c2v[4];
  #pragma unroll
  for (int n = 0; n < 4; ++n) c2v[n] = c2[colB0 + wc * 64 + n * 16 + ln15];

  unsigned* mb = (unsigned*)smem;  // [128 rows][2 wc][4 words]
  #pragma unroll
  for (int m = 0; m < 4; ++m) {
    #pragma unroll
    for (int rr = 0; rr < 4; ++rr) {
      unsigned k1 = 0xFFFFFFFFu, k2 = 0xFFFFFFFFu, k3 = 0xFFFFFFFFu;
      #pragma unroll
      for (int n = 0; n < 4; ++n) {
        float q = fmaf(-2.0f, acc[m][n][rr], c2v[n]);
        unsigned u = __float_as_uint(q);
        unsigned msk = 0x80000000u | (unsigned)((int)u >> 31);
        unsigned key = ((u ^ msk) & 0xFFFFFFC0u) | (unsigned)(n * 16 + ln15);
        unsigned t1 = umax_(k1, key);
        k1 = umin_(k1, key);
        unsigned t2 = umax_(k2, t1);
        k2 = umin_(k2, t1);
        k3 = umin_(k3, t2);
      }
      #pragma unroll
      for (int sh = 1; sh <= 8; sh <<= 1) {
        unsigned o1 = (unsigned)__shfl_xor((int)k1, sh);
        unsigned o2 = (unsigned)__shfl_xor((int)k2, sh);
        unsigned o3 = (unsigned)__shfl_xor((int)k3, sh);
        unsigned mm = umax_(k1, o1);
        k1 = umin_(k1, o1);
        unsigned tt = umin_(k2, o2);
        k2 = umin_(mm, tt);
        k3 = umin_(umin_(k3, o3), umax_(mm, tt));
      }
      if (ln15 == 0) {
        int row = wr * 64 + m * 16 + ln4 * 4 + rr;
        unsigned* p = mb + (row * 2 + wc) * 4;
        p[0] = k1; p[1] = k2; p[2] = k3;
      }
    }
  }
  __syncthreads();
  if (tid < 128) {
    const unsigned* p0 = mb + (tid * 2) * 4;
    const unsigned* p1 = mb + (tid * 2 + 1) * 4;
    auto dec = [](unsigned k) -> float {
      unsigned u = k & 0xFFFFFFC0u;
      u = (u & 0x80000000u) ? (u ^ 0x80000000u) : ~u;
      return __uint_as_float(u);
    };
    float m1 = dec(p0[0]); int i1 = colB0 + (int)(p0[0] & 63u);
    float m2 = dec(p0[1]); int i2 = colB0 + (int)(p0[1] & 63u);
    float m3 = dec(p0[2]);
    rec_ins(m1, m2, m3, i1, i2, dec(p1[0]), colB0 + 64 + (int)(p1[0] & 63u));
    rec_ins(m1, m2, m3, i1, i2, dec(p1[1]), colB0 + 64 + (int)(p1[1] & 63u));
    m3 = fminf(m3, dec(p1[2]));
    Rec16 outr;
    outr.m1 = m1; outr.m2 = m2; outr.m3 = m3;
    outr.ii = (unsigned)i1 | ((unsigned)i2 << 16);
    recs[((size_t)(rowOff + rowA0 + tid) << 4) + colblk] = outr;
  }
}

// ---------------- merge 16 col-block records; classify; hist ------------
__global__ __launch_bounds__(256) void k_merge(
    const Rec16* __restrict__ recs, int* __restrict__ labels,
    int4* __restrict__ pairs, int* __restrict__ scans,
    int* __restrict__ npairs, int* __restrict__ nscan, int* __restrict__ cnt) {
  int row = blockIdx.x * 256 + threadIdx.x;
  const Rec16* r = recs + ((size_t)row << 4);
  Rec16 a = r[0];
  float m1 = a.m1, m2 = a.m2, m3 = a.m3;
  int i1 = (int)(a.ii & 0xffffu), i2 = (int)(a.ii >> 16);
  #pragma unroll
  for (int cb = 1; cb < 16; ++cb) {
    Rec16 bb = r[cb];
    rec_ins(m1, m2, m3, i1, i2, bb.m1, (int)(bb.ii & 0xffffu));
    rec_ins(m1, m2, m3, i1, i2, bb.m2, (int)(bb.ii >> 16));
    m3 = fminf(m3, bb.m3);
  }
  labels[row] = i1;
  atomicAdd(&cnt[i1], 1);  // provisional; corrected by pairs/scan on change
  if (m2 <= m1 + SMARGIN) {
    if (m3 <= m1 + SMARGIN) {
      int s = atomicAdd(nscan, 1); scans[s] = row;
    } else {
      int p = atomicAdd(npairs, 1); pairs[p] = make_int4(row, i1, i2, 0);
    }
  }
}

// ---------------- exact rescore: 2-candidate rows ----------------
__global__ __launch_bounds__(256) void k_pairs(
    const float* __restrict__ E, const float* __restrict__ C,
    const float* __restrict__ x2, const float* __restrict__ c2,
    const int4* __restrict__ pairs, const int* __restrict__ npairs,
    int* __restrict__ labels, int* __restrict__ cnt) {
  int n = *npairs;
  int stride = gridDim.x * 256;
  for (int i = blockIdx.x * 256 + threadIdx.x; i < n; i += stride) {
    int4 p = pairs[i];
    float d1 = dist_exact(E, C, x2, c2, p.x, p.y);
    float d2 = dist_exact(E, C, x2, c2, p.x, p.z);
    int nw = (d2 < d1 || (d2 == d1 && p.z < p.y)) ? p.z : p.y;
    if (nw != p.y) {
      labels[p.x] = nw;
      atomicSub(&cnt[p.y], 1);
      atomicAdd(&cnt[nw], 1);
    }
  }
}

// ---------------- exact rescore: full-scan rows ----------------
__global__ __launch_bounds__(256) void k_scan(
    const float* __restrict__ E, const float* __restrict__ C,
    const float* __restrict__ x2, const float* __restrict__ c2,
    const int* __restrict__ scans, const int* __restrict__ nscan,
    int* __restrict__ labels, int* __restrict__ cnt) {
  __shared__ float sd[256];
  __shared__ int sj[256];
  int ns = *nscan;
  for (int s = blockIdx.x; s < ns; s += gridDim.x) {
    int row = scans[s];
    float bd = 3.4e38f; int bj = 0x7fffffff;
    for (int jj = 0; jj < 8; ++jj) {
      int j = jj * 256 + threadIdx.x;
      float d = dist_exact(E, C, x2, c2, row, j);
      if (d < bd || (d == bd && j < bj)) { bd = d; bj = j; }
    }
    sd[threadIdx.x] = bd; sj[threadIdx.x] = bj;
    __syncthreads();
    for (int st = 128; st > 0; st >>= 1) {
      if (threadIdx.x < st) {
        float od = sd[threadIdx.x + st]; int oj = sj[threadIdx.x + st];
        if (od < sd[threadIdx.x] || (od == sd[threadIdx.x] && oj < sj[threadIdx.x])) {
          sd[threadIdx.x] = od; sj[threadIdx.x] = oj;
        }
      }
      __syncthreads();
    }
    if (threadIdx.x == 0) {
      int nw = sj[0];
      int old = labels[row];
      if (nw != old) {
        labels[row] = nw;
        atomicSub(&cnt[old], 1);
        atomicAdd(&cnt[nw], 1);
      }
    }
    __syncthreads();
  }
}

// ---------------- exclusive scan over 2048 counts (Blelloch) ------------
__global__ __launch_bounds__(1024) void k_prefix(const int* __restrict__ cnt,
                                                 int* __restrict__ offs,
                                                 int* __restrict__ cursors) {
  __shared__ int s[KC];
  int t = threadIdx.x;
  s[t] = cnt[t]; s[t + 1024] = cnt[t + 1024];
  int offset = 1;
  for (int d = KC >> 1; d > 0; d >>= 1) {
    __syncthreads();
    if (t < d) {
      int ai = offset * (2 * t + 1) - 1;
      int bi = offset * (2 * t + 2) - 1;
      s[bi] += s[ai];
    }
    offset <<= 1;
  }
  __syncthreads();
  if (t == 0) s[KC - 1] = 0;
  for (int d = 1; d < KC; d <<= 1) {
    offset >>= 1;
    __syncthreads();
    if (t < d) {
      int ai = offset * (2 * t + 1) - 1;
      int bi = offset * (2 * t + 2) - 1;
      int tmp = s[ai]; s[ai] = s[bi]; s[bi] += tmp;
    }
  }
  __syncthreads();
  offs[t] = s[t];               cursors[t] = s[t];
  offs[t + 1024] = s[t + 1024]; cursors[t + 1024] = s[t + 1024];
  if (t == 0) offs[KC] = NS;
}

// ---------------- scatter rows into label-sorted order (+label array) ----
__global__ void k_scatter(const int* __restrict__ labels, int* __restrict__ cursors,
                          int* __restrict__ sorted, int* __restrict__ slab,
                          float* __restrict__ out_labels) {
  int i = blockIdx.x * 256 + threadIdx.x;
  if (i < NS) {
    int lab = labels[i];
    out_labels[i] = (float)lab;
    int pos = atomicAdd(&cursors[lab], 1);
    sorted[pos] = i;
    slab[pos] = lab;
  }
}

// ---------------- balanced segmented accumulate over sorted rows --------
__global__ __launch_bounds__(256) void k_accum3(
    const float* __restrict__ E, const float* __restrict__ C,
    const int* __restrict__ sorted, const int* __restrict__ slab,
    float* __restrict__ seg, double* __restrict__ loss) {
  const int d = threadIdx.x;
  const int beg = blockIdx.x * ACHUNK;
  const int end = beg + ACHUNK;
  int cur = slab[beg];
  float sum = 0.0f;
  double lp = 0.0;
  for (int i = beg; i < end; ++i) {
    int lab = slab[i];
    if (lab != cur) {
      unsafeAtomicAdd(&seg[(size_t)cur * DD + d], sum);
      sum = 0.0f; cur = lab;
    }
    float x = E[(size_t)sorted[i] * DD + d];
    sum += x;
    float c = C[(size_t)lab * DD + d];
    float df = x - c;
    lp += (double)df * (double)df;
  }
  unsafeAtomicAdd(&seg[(size_t)cur * DD + d], sum);
  #pragma unroll
  for (int o = 32; o >= 1; o >>= 1) lp += __shfl_down(lp, o);
  __shared__ double wsum[4];
  int lane = d & 63, wv = d >> 6;
  if (lane == 0) wsum[wv] = lp;
  __syncthreads();
  if (d == 0) unsafeAtomicAdd(loss, wsum[0] + wsum[1] + wsum[2] + wsum[3]);
}

// ---------------- finalize centers, counts, loss ----------------
__global__ void k_final2(const float* __restrict__ C, const int* __restrict__ counts0,
                         const int* __restrict__ offs, float* __restrict__ out_centers,
                         float* __restrict__ out_counts, float* __restrict__ out_loss,
                         const double* __restrict__ loss) {
  int i = blockIdx.x * 256 + threadIdx.x;
  if (i < KC * DD) {
    int k = i >> 8;
    float c0 = (float)counts0[k];
    float nc = c0 + (float)(offs[k + 1] - offs[k]);
    out_centers[i] = (c0 * C[i] + out_centers[i]) / nc;
  }
  if (i < KC) out_counts[i] = (float)counts0[i] + (float)(offs[i + 1] - offs[i]);
  if (i == 0) out_loss[0] = (float)(loss[0] / (double)NS);
}

extern "C" void kernel_launch(void* const* d_in, const int* in_sizes, int n_in,
                              void* d_out, int out_size, void* d_ws, size_t ws_size,
                              hipStream_t stream) {
  const float* E = (const float*)d_in[0];
  const float* C = (const float*)d_in[1];
  const int* counts0 = (const int*)d_in[2];

  float* out = (float*)d_out;
  float* out_labels  = out;                     // [NS]
  float* out_loss    = out + NS;                // [1]
  float* out_centers = out + NS + 1;            // [KC*DD] (doubles as seg acc)
  float* out_counts  = out + NS + 1 + KC * DD;  // [KC]

  char* ws = (char*)d_ws;
  size_t o = 0;
  auto alloc = [&](size_t bytes) -> void* {
    void* p = ws + o;
    o += (bytes + 255) & ~(size_t)255;
    return p;
  };
  // zero-region: loss(8) @0, npairs @16, nscan @20, cnt[KC] @256
  char* zr = (char*)alloc(256 + 4 * KC);        // 8448 bytes zeroed by memset
  double* loss_acc = (double*)zr;
  int* npairs = (int*)(zr + 16);
  int* nscan  = (int*)(zr + 20);
  int* cnt    = (int*)(zr + 256);
  int*   labels  = (int*)alloc(4 * (size_t)NS);
  float* x2      = (float*)alloc(4 * (size_t)NS);
  float* c2      = (float*)alloc(4 * KC);
  int*   offs    = (int*)alloc(4 * (KC + 1));
  int*   cursors = (int*)alloc(4 * KC);
  int*   sorted  = (int*)alloc(4 * (size_t)NS);
  int*   slab    = (int*)alloc(4 * (size_t)NS);
  unsigned short* CX = (unsigned short*)alloc(2 * (size_t)KC * 256);
  Rec16* recs    = (Rec16*)alloc(sizeof(Rec16) * (size_t)NS * 16);
  int4*  pairs   = (int4*)alloc(16 * (size_t)NS);
  int*   scans   = (int*)alloc(4 * (size_t)NS);

  // EX chunk (rows of 256 fp16 = 512 B): full NS if it fits, else halve
  size_t avail = (ws_size > o) ? (ws_size - o) : 0;
  int CH = NS;
  while (CH > 2048 && (size_t)CH * 512 > avail) CH >>= 1;
  unsigned short* EX = (unsigned short*)alloc((size_t)CH * 512);
  int NCH = NS / CH;

  hipMemsetAsync(zr, 0, 256 + 4 * KC, stream);
  hipMemsetAsync(out_centers, 0, sizeof(float) * KC * DD, stream);

  hipLaunchKernelGGL(k_prep, dim3(KC / 32), dim3(256), 0, stream, C, c2, CX);

  for (int ch = 0; ch < NCH; ++ch) {
    hipLaunchKernelGGL(k_prep, dim3(CH / 32), dim3(256), 0, stream,
                       E + (size_t)ch * CH * DD, x2 + (size_t)ch * CH, EX);
    hipLaunchKernelGGL(k_screen16, dim3((CH / 128) * 16), dim3(256), 0, stream,
                       EX, CX, c2, recs, ch * CH);
  }

  hipLaunchKernelGGL(k_merge, dim3(NS / 256), dim3(256), 0, stream,
                     recs, labels, pairs, scans, npairs, nscan, cnt);
  hipLaunchKernelGGL(k_pairs, dim3(64), dim3(256), 0, stream,
                     E, C, x2, c2, pairs, npairs, labels, cnt);
  hipLaunchKernelGGL(k_scan, dim3(128), dim3(256), 0, stream,
                     E, C, x2, c2, scans, nscan, labels, cnt);
  hipLaunchKernelGGL(k_prefix, dim3(1), dim3(1024), 0, stream, cnt, offs, cursors);
  hipLaunchKernelGGL(k_scatter, dim3(NS / 256), dim3(256), 0, stream,
                     labels, cursors, sorted, slab, out_labels);
  hipLaunchKernelGGL(k_accum3, dim3(NS / ACHUNK), dim3(256), 0, stream,
                     E, C, sorted, slab, out_centers, loss_acc);
  hipLaunchKernelGGL(k_final2, dim3((KC * DD + 255) / 256), dim3(256), 0, stream,
                     C, counts0, offs, out_centers, out_counts, out_loss, loss_acc);
}